// Round 11
// baseline (520.761 us; speedup 1.0000x reference)
//
#include <hip/hip_runtime.h>
#include <math.h>

#define N_NODES 192000
#define EDGES   2000000
#define HID     64
#define BN_ROWS 16000   // B*NN
#define T_WIN   12
#define B_SZ    8
#define NN_SZ   2000
#define FIN     8
#define BN_EPS  1e-5f

// two-level bucket sort params: bucket = col >> 8 (256 nodes/bucket)
#define NBKT    750
#define NBLKA   256
#define ACHUNK  7824     // 256*7824 = 2,002,944 >= EDGES, divisible by 4
#define BKT_CAP 5120     // mean bucket = 2667, +47 sigma headroom

typedef _Float16 f16x2 __attribute__((ext_vector_type(2)));
typedef _Float16 half4 __attribute__((ext_vector_type(4)));
typedef _Float16 half8 __attribute__((ext_vector_type(8)));
typedef float    f32x4 __attribute__((ext_vector_type(4)));
union F16x2U { float f; f16x2 h; };

// fast sigmoid/tanh: v_exp_f32 + v_rcp_f32 (~1 ulp; f16 inputs dominate error)
__device__ __forceinline__ float frcp(float x){
#if __has_builtin(__builtin_amdgcn_rcpf)
    return __builtin_amdgcn_rcpf(x);
#else
    return 1.0f/x;
#endif
}
__device__ __forceinline__ float fsig(float x){ return frcp(1.0f + __expf(-x)); }
__device__ __forceinline__ float ftanh(float x){ return fmaf(2.0f, fsig(2.0f*x), -1.0f); }

__device__ __forceinline__ float packf16(float a, float b){
    F16x2U u; u.h[0] = (_Float16)a; u.h[1] = (_Float16)b; return u.f;
}

// R23: LDS-only barrier. __syncthreads makes hipcc emit s_waitcnt vmcnt(0)
// lgkmcnt(0) before s_barrier -> every outstanding global load (weight frags,
// h1H/g2H prefetch) is force-drained at each barrier, exposing ~500+ cyc of
// memory latency per step (R22 showed time invariant to occupancy AND to
// weight-load elimination -> per-step path is the bound). Raw s_barrier +
// lgkmcnt(0)-only preserves LDS ordering (each wave drains its own ds ops
// before the barrier) while global loads wait only at their register use
// (compiler-inserted counted vmcnt). sched_barrier(0) per rule #18.
__device__ __forceinline__ void lds_barrier(){
    asm volatile("s_waitcnt lgkmcnt(0)" ::: "memory");
    __builtin_amdgcn_s_barrier();
    __builtin_amdgcn_sched_barrier(0);
}

// ---------- pass A: per-block LDS histogram over coarse buckets ----------
__global__ __launch_bounds__(256) void hist_coarse(
        const int* __restrict__ col, unsigned* __restrict__ gcount,
        int* __restrict__ blockbase){
    __shared__ unsigned bh[NBKT];
    int bl = blockIdx.x, tid = threadIdx.x;
    for (int i = tid; i < NBKT; i += 256) bh[i] = 0u;
    __syncthreads();
    int e0 = bl*ACHUNK;
    int e1 = e0 + ACHUNK; if (e1 > EDGES) e1 = EDGES;
    for (int e = e0 + tid*4; e < e1; e += 1024){
        int4 c4 = *(const int4*)&col[e];
        atomicAdd(&bh[((unsigned)c4.x) >> 8], 1u);
        atomicAdd(&bh[((unsigned)c4.y) >> 8], 1u);
        atomicAdd(&bh[((unsigned)c4.z) >> 8], 1u);
        atomicAdd(&bh[((unsigned)c4.w) >> 8], 1u);
    }
    __syncthreads();
    for (int i = tid; i < NBKT; i += 256)
        blockbase[bl*NBKT + i] = (int)atomicAdd(&gcount[i], bh[i]);
}

// ---------- scan of 750 bucket totals ----------
__global__ __launch_bounds__(1024) void scan_bkt(
        const unsigned* __restrict__ gcount, int* __restrict__ gbase,
        int* __restrict__ offsets){
    __shared__ int sm[1024];
    int tid = threadIdx.x;
    int v = (tid < NBKT) ? (int)gcount[tid] : 0;
    sm[tid] = v;
    __syncthreads();
    #pragma unroll
    for (int off = 1; off < 1024; off <<= 1){
        int t = (tid >= off) ? sm[tid - off] : 0;
        __syncthreads();
        sm[tid] += t;
        __syncthreads();
    }
    if (tid < NBKT) gbase[tid] = sm[tid] - v;
    if (tid == NBKT) gbase[NBKT] = EDGES;
    if (tid == NBKT+1) offsets[N_NODES] = EDGES;
}

// ---------- pass B: scatter edges into bucket regions (LDS cursors) ----------
__global__ __launch_bounds__(256) void scatter_bucket(
        const int* __restrict__ row, const int* __restrict__ col,
        const float* __restrict__ w, const int* __restrict__ blockbase,
        const int* __restrict__ gbase, int2* __restrict__ rec){
    __shared__ unsigned cur[NBKT];
    int bl = blockIdx.x, tid = threadIdx.x;
    for (int i = tid; i < NBKT; i += 256)
        cur[i] = (unsigned)(gbase[i] + blockbase[bl*NBKT + i]);
    __syncthreads();
    int e0 = bl*ACHUNK;
    int e1 = e0 + ACHUNK; if (e1 > EDGES) e1 = EDGES;
    for (int e = e0 + tid*4; e < e1; e += 1024){
        int4 r4 = *(const int4*)&row[e];
        int4 c4 = *(const int4*)&col[e];
        float4 w4 = *(const float4*)&w[e];
        int cc[4] = {c4.x, c4.y, c4.z, c4.w};
        int rr[4] = {r4.x, r4.y, r4.z, r4.w};
        float wf[4] = {w4.x, w4.y, w4.z, w4.w};
        #pragma unroll
        for (int q = 0; q < 4; q++){
            int c = cc[q];
            unsigned wfix = (unsigned)(wf[q]*16777216.0f + 0.5f);
            if (wfix > 0xFFFFFFu) wfix = 0xFFFFFFu;
            unsigned p = atomicAdd(&cur[((unsigned)c) >> 8], 1u);
            int2 rv; rv.x = rr[q];
            rv.y = (int)((((unsigned)(c & 255)) << 24) | wfix);
            rec[p] = rv;
        }
    }
}

// ---------- per-bucket weighted degree -> dis, before CSR build ----------
// (dis[r.x] in bucket_csr needs ALL buckets' dis -> cannot merge with csr.)
__global__ __launch_bounds__(256) void bucket_deg(
        const int2* __restrict__ rec, const int* __restrict__ gbase,
        float* __restrict__ dis){
    __shared__ unsigned wsum[256];
    int b = blockIdx.x, tid = threadIdx.x;
    wsum[tid] = 0u;
    __syncthreads();
    int k0 = gbase[b], k1 = gbase[b+1];
    for (int i = k0 + tid; i < k1; i += 256){
        int2 r = rec[i];
        atomicAdd(&wsum[((unsigned)r.y) >> 24], ((unsigned)r.y) & 0xFFFFFFu);
    }
    __syncthreads();
    float deg = (float)wsum[tid] * (1.0f/16777216.0f);
    dis[(b<<8) + tid] = rsqrtf(deg + 1.0f);   // + self-loop weight
}

// ---------- pass C: per-bucket exact CSR build, all in LDS ----------
// edge_s.x packs clow<<24 | row; edge_s.y = dis[r]*w*dis[c] fully folded.
__global__ __launch_bounds__(256) void bucket_csr(
        const int2* __restrict__ rec, const int* __restrict__ gbase,
        const float* __restrict__ dis,
        int2* __restrict__ edge_s, int* __restrict__ offsets){
    __shared__ int2 S[BKT_CAP];
    __shared__ unsigned cnt[256];
    __shared__ unsigned cur[256];
    __shared__ float dloc[256];
    int b = blockIdx.x, tid = threadIdx.x;
    int k0 = gbase[b], k1 = gbase[b+1];
    int n = k1 - k0;
    cnt[tid] = 0u;
    dloc[tid] = dis[(b<<8) + tid];
    __syncthreads();
    bool staged = (n <= BKT_CAP);
    for (int i = tid; i < n; i += 256){
        int2 r = rec[k0 + i];
        if (staged) S[i] = r;
        atomicAdd(&cnt[((unsigned)r.y) >> 24], 1u);
    }
    __syncthreads();
    unsigned v = cnt[tid];
    #pragma unroll
    for (int off = 1; off < 256; off <<= 1){
        unsigned t = (tid >= off) ? cnt[tid - off] : 0u;
        __syncthreads();
        cnt[tid] += t;
        __syncthreads();
    }
    unsigned excl = cnt[tid] - v;
    cur[tid] = excl;
    offsets[(b<<8) + tid] = k0 + (int)excl;
    __syncthreads();
    for (int i = tid; i < n; i += 256){
        int2 r = staged ? S[i] : rec[k0 + i];
        unsigned clow = ((unsigned)r.y) >> 24;
        unsigned wfix = ((unsigned)r.y) & 0xFFFFFFu;
        float sv = (float)wfix * (1.0f/16777216.0f) * dloc[clow];
        sv = dis[r.x] * sv;
        unsigned p = atomicAdd(&cur[clow], 1u);
        int2 o; o.x = (int)((clow << 24) | (unsigned)r.x); o.y = __float_as_int(sv);
        edge_s[k0 + (int)p] = o;
    }
}

// ---------- layer-1 aggregation, node-parallel (known-good) ----------
// R17-R19 lesson: edge-parallel LDS-atomic variants all ~90us; this form ~40us.
__global__ __launch_bounds__(256) void aggx_k(
        const int* __restrict__ offsets, const int2* __restrict__ edge_s,
        const float* __restrict__ dis, const float* __restrict__ x,
        float* __restrict__ ax){
    int g   = blockIdx.x*32 + (threadIdx.x >> 3);
    int sub = threadIdx.x & 7;
    float d = dis[g];
    float acc = x[(size_t)g*8 + sub]*d*d;
    int k  = offsets[g];
    int k1 = offsets[g+1];
    for (; k+4 <= k1; k += 4){
        int2 e0 = edge_s[k], e1 = edge_s[k+1], e2 = edge_s[k+2], e3 = edge_s[k+3];
        float v0 = x[(size_t)(e0.x & 0xFFFFFF)*8 + sub];
        float v1 = x[(size_t)(e1.x & 0xFFFFFF)*8 + sub];
        float v2 = x[(size_t)(e2.x & 0xFFFFFF)*8 + sub];
        float v3 = x[(size_t)(e3.x & 0xFFFFFF)*8 + sub];
        acc += v0*__int_as_float(e0.y);
        acc += v1*__int_as_float(e1.y);
        acc += v2*__int_as_float(e2.y);
        acc += v3*__int_as_float(e3.y);
    }
    for (; k < k1; k++){
        int2 e0 = edge_s[k];
        acc += x[(size_t)(e0.x & 0xFFFFFF)*8 + sub]*__int_as_float(e0.y);
    }
    ax[(size_t)g*8 + sub] = acc;
}

// ---------- gcnA1 = relu(ax @ W1 + b1), fused BN1 stats ----------
__global__ __launch_bounds__(256) void lin1b_stats(
        const float* __restrict__ ax, const float* __restrict__ W1,
        const float* __restrict__ b1, float* __restrict__ out,
        float* __restrict__ gsum, float* __restrict__ gsq){
    __shared__ float Ws[512];
    for (int i = threadIdx.x; i < 512; i += 256) Ws[i] = W1[i];
    __syncthreads();
    int f = threadIdx.x & 63;
    float wc[8];
    #pragma unroll
    for (int q = 0; q < 8; q++) wc[q] = Ws[q*64 + f];
    float bb = b1[f];
    float s = 0.f, s2 = 0.f;
    int stride = gridDim.x*blockDim.x;   // multiple of 64
    for (int idx = blockIdx.x*blockDim.x + threadIdx.x; idx < N_NODES*64; idx += stride){
        int j = idx >> 6;
        const float* ar = ax + (size_t)j*8;
        float acc = bb;
        #pragma unroll
        for (int q = 0; q < 8; q++) acc += ar[q]*wc[q];
        float v = fmaxf(acc, 0.f);
        out[idx] = v;
        s += v; s2 += v*v;
    }
    __shared__ float s1m[256], s2m[256];
    s1m[threadIdx.x] = s; s2m[threadIdx.x] = s2;
    __syncthreads();
    if (threadIdx.x < 64){
        float t1 = s1m[threadIdx.x]+s1m[threadIdx.x+64]+s1m[threadIdx.x+128]+s1m[threadIdx.x+192];
        float t2 = s2m[threadIdx.x]+s2m[threadIdx.x+64]+s2m[threadIdx.x+128]+s2m[threadIdx.x+192];
        atomicAdd(&gsum[threadIdx.x], t1);
        atomicAdd(&gsq[threadIdx.x], t2);
    }
}

// ---------- lin2_bn: h1H = f16(BN(gcnA1)); hlinH = pack_f16(BN(gcnA1) @ W2) ----------
#define L2ROWS 128
#define XS2    132
__global__ __launch_bounds__(128) void lin2_bn(
        const float* __restrict__ gcnA, const float* __restrict__ gsum,
        const float* __restrict__ gsq, const float* __restrict__ g1,
        const float* __restrict__ be1, const float* __restrict__ W2,
        _Float16* __restrict__ h1H, float* __restrict__ hlinH){
    __shared__ float Ws[64*64];
    __shared__ float xsT[64*XS2];
    int tid = threadIdx.x;
    int r0 = blockIdx.x * L2ROWS;

    for (int i = tid; i < 1024; i += 128)
        *(float4*)&Ws[i*4] = *(const float4*)&W2[i*4];

    int k4 = tid & 15;
    int rb = tid >> 4;
    float scv[4], shv[4];
    #pragma unroll
    for (int q = 0; q < 4; q++){
        int f = k4*4 + q;
        float mean = gsum[f]*(1.0f/(float)N_NODES);
        float var  = fmaxf(gsq[f]*(1.0f/(float)N_NODES) - mean*mean, 0.f);
        float sc_  = g1[f]*rsqrtf(var + BN_EPS);
        scv[q] = sc_; shv[q] = be1[f] - mean*sc_;
    }
    for (int it = 0; it < 16; it++){
        int r = it*8 + rb;
        float4 v = *(const float4*)&gcnA[(size_t)(r0+r)*64 + k4*4];
        v.x = v.x*scv[0]+shv[0]; v.y = v.y*scv[1]+shv[1];
        v.z = v.z*scv[2]+shv[2]; v.w = v.w*scv[3]+shv[3];
        half4 hh;
        hh[0]=(_Float16)v.x; hh[1]=(_Float16)v.y; hh[2]=(_Float16)v.z; hh[3]=(_Float16)v.w;
        *(half4*)&h1H[(size_t)(r0+r)*64 + k4*4] = hh;
        xsT[(k4*4+0)*XS2 + r] = v.x;
        xsT[(k4*4+1)*XS2 + r] = v.y;
        xsT[(k4*4+2)*XS2 + r] = v.z;
        xsT[(k4*4+3)*XS2 + r] = v.w;
    }
    __syncthreads();

    int cg = tid & 7;
    int rg = tid >> 3;
    float acc[8][8];
    #pragma unroll
    for (int i = 0; i < 8; i++)
        #pragma unroll
        for (int j = 0; j < 8; j++) acc[i][j] = 0.f;

    float4 a0 = *(float4*)&xsT[0*XS2 + rg*8];
    float4 a1 = *(float4*)&xsT[0*XS2 + rg*8 + 4];
    float4 w0 = *(float4*)&Ws[0*64 + cg*8];
    float4 w1 = *(float4*)&Ws[0*64 + cg*8 + 4];
    for (int k = 0; k < 64; k++){
        float4 na0, na1, nw0, nw1;
        if (k < 63){
            na0 = *(float4*)&xsT[(k+1)*XS2 + rg*8];
            na1 = *(float4*)&xsT[(k+1)*XS2 + rg*8 + 4];
            nw0 = *(float4*)&Ws[(k+1)*64 + cg*8];
            nw1 = *(float4*)&Ws[(k+1)*64 + cg*8 + 4];
        }
        float ar[8] = {a0.x,a0.y,a0.z,a0.w,a1.x,a1.y,a1.z,a1.w};
        float wcv[8] = {w0.x,w0.y,w0.z,w0.w,w1.x,w1.y,w1.z,w1.w};
        #pragma unroll
        for (int i = 0; i < 8; i++)
            #pragma unroll
            for (int j = 0; j < 8; j++) acc[i][j] += ar[i]*wcv[j];
        a0=na0; a1=na1; w0=nw0; w1=nw1;
    }
    #pragma unroll
    for (int i = 0; i < 8; i++){
        size_t r = (size_t)(r0 + rg*8 + i);
        float4 pk;
        pk.x = packf16(acc[i][0], acc[i][1]);
        pk.y = packf16(acc[i][2], acc[i][3]);
        pk.z = packf16(acc[i][4], acc[i][5]);
        pk.w = packf16(acc[i][6], acc[i][7]);
        *(float4*)&hlinH[r*32 + cg*4] = pk;
    }
}

// ---------- layer-2 gather over packed f16 rows, one-shot grid (max MLP) ----------
__global__ __launch_bounds__(256) void gather2h(
        const int* __restrict__ offsets, const int2* __restrict__ edge_s,
        const float* __restrict__ dis, const float* __restrict__ hlinH,
        const float* __restrict__ bias, float* __restrict__ g2Hf){
    int j = blockIdx.x*8 + (threadIdx.x >> 5);
    int p = threadIdx.x & 31;
    float d = dis[j];
    float dd = d*d;
    F16x2U u; u.f = hlinH[(size_t)j*32 + p];
    float ax = (float)u.h[0]*dd;
    float ay = (float)u.h[1]*dd;
    int k  = offsets[j];
    int k1 = offsets[j+1];
    for (; k+4 <= k1; k += 4){
        int2 e0 = edge_s[k], e1 = edge_s[k+1], e2 = edge_s[k+2], e3 = edge_s[k+3];
        F16x2U a, b, c, e;
        a.f = hlinH[(size_t)(e0.x & 0xFFFFFF)*32 + p];
        b.f = hlinH[(size_t)(e1.x & 0xFFFFFF)*32 + p];
        c.f = hlinH[(size_t)(e2.x & 0xFFFFFF)*32 + p];
        e.f = hlinH[(size_t)(e3.x & 0xFFFFFF)*32 + p];
        float n0 = __int_as_float(e0.y), n1 = __int_as_float(e1.y);
        float n2 = __int_as_float(e2.y), n3 = __int_as_float(e3.y);
        ax += (float)a.h[0]*n0; ay += (float)a.h[1]*n0;
        ax += (float)b.h[0]*n1; ay += (float)b.h[1]*n1;
        ax += (float)c.h[0]*n2; ay += (float)c.h[1]*n2;
        ax += (float)e.h[0]*n3; ay += (float)e.h[1]*n3;
    }
    for (; k < k1; k++){
        int2 e0 = edge_s[k];
        F16x2U a; a.f = hlinH[(size_t)(e0.x & 0xFFFFFF)*32 + p];
        float n0 = __int_as_float(e0.y);
        ax += (float)a.h[0]*n0; ay += (float)a.h[1]*n0;
    }
    float2 bv = *(const float2*)&bias[2*p];
    float vx = fmaxf(ax + bv.x, 0.f);
    float vy = fmaxf(ay + bv.y, 0.f);
    F16x2U o; o.h[0] = (_Float16)vx; o.h[1] = (_Float16)vy;
    g2Hf[(size_t)j*32 + p] = o.f;
}

// ---------- BN2 stats over f16 output (12.3 MB pass) ----------
__global__ __launch_bounds__(256) void stats2h(
        const float* __restrict__ g2Hf, float* __restrict__ gsum2, float* __restrict__ gsq2){
    int p = threadIdx.x & 31;
    float s0 = 0.f, s1 = 0.f, q0 = 0.f, q1 = 0.f;
    int stride = gridDim.x*blockDim.x;   // multiple of 32 -> p constant
    for (int idx = blockIdx.x*blockDim.x + threadIdx.x; idx < N_NODES*32; idx += stride){
        F16x2U u; u.f = g2Hf[idx];
        float vx = (float)u.h[0], vy = (float)u.h[1];
        s0 += vx; q0 += vx*vx;
        s1 += vy; q1 += vy*vy;
    }
    __shared__ float sb[128];
    if (threadIdx.x < 128) sb[threadIdx.x] = 0.f;
    __syncthreads();
    atomicAdd(&sb[2*p],      s0);
    atomicAdd(&sb[2*p+1],    s1);
    atomicAdd(&sb[64+2*p],   q0);
    atomicAdd(&sb[64+2*p+1], q1);
    __syncthreads();
    if (threadIdx.x < 64){
        atomicAdd(&gsum2[threadIdx.x], sb[threadIdx.x]);
        atomicAdd(&gsq2[threadIdx.x],  sb[64+threadIdx.x]);
    }
}

// ---------- LSTM weight prep: B-fragment layout [K/32][256][32] f16 ----------
__global__ void prep_weights(const float* __restrict__ Wih1, const float* __restrict__ Whh1,
                             const float* __restrict__ bih1, const float* __restrict__ bhh1,
                             const float* __restrict__ Wih2, const float* __restrict__ Whh2,
                             const float* __restrict__ bih2, const float* __restrict__ bhh2,
                             _Float16* W1F, _Float16* W2F, float* b1c, float* b2c){
    int idx = blockIdx.x*blockDim.x + threadIdx.x;
    if (idx < 6*256*32){
        int kt = idx >> 13;
        int rem = idx & 8191;
        int n = rem >> 5, kin = rem & 31;
        int k = kt*32 + kin;
        float v = (k < 128) ? Wih1[n*128 + k] : Whh1[n*64 + (k-128)];
        W1F[idx] = (_Float16)v;
    }
    int i2 = idx - 6*256*32;
    if (i2 >= 0 && i2 < 4*256*32){
        int kt = i2 >> 13;
        int rem = i2 & 8191;
        int n = rem >> 5, kin = rem & 31;
        int k = kt*32 + kin;
        float v = (k < 64) ? Wih2[n*64 + k] : Whh2[n*64 + (k-64)];
        W2F[i2] = (_Float16)v;
    }
    int i3 = idx - (6*256*32 + 4*256*32);
    if (i3 >= 0 && i3 < 256) b1c[i3] = bih1[i3] + bhh1[i3];
    int i4 = i3 - 256;
    if (i4 >= 0 && i4 < 256) b2c[i4] = bih2[i4] + bhh2[i4];
}

// ---------- fused 12-step LSTM1+LSTM2, MFMA 16x16x32 f16, 32 rows/block ----------
// R21 structure (77.5us, VGPR 196, 2 barriers/step) + R23 raw LDS-only
// barriers (see lds_barrier above). R22 falsified the weight-load and
// occupancy theories; the barrier vmcnt(0) drain is the remaining candidate
// for the 15.5K cyc/step vs ~1-2K computed gap.
#define X1S 200   // halves/row, 400 B
#define X2S 136   // halves/row, 272 B
__global__ __launch_bounds__(256) void lstm_fused(
        const _Float16* __restrict__ h1H, const _Float16* __restrict__ g2H,
        const float* __restrict__ gsum2, const float* __restrict__ gsq2,
        const float* __restrict__ g2bn, const float* __restrict__ be2,
        const _Float16* __restrict__ W1F, const _Float16* __restrict__ W2F,
        const float* __restrict__ b1c, const float* __restrict__ b2c,
        float* __restrict__ h1s, float* __restrict__ h2s){
    __shared__ _Float16 X1h[32*X1S];
    __shared__ _Float16 X2h[32*X2S];
    int tid = threadIdx.x;
    int j0 = blockIdx.x*32;
    int w    = tid >> 6;
    int lane = tid & 63;
    int quad = lane >> 4;
    int l16  = lane & 15;
    int u    = 16*w + l16;

    int c4 = tid & 15;
    int sr = (tid >> 4) & 15;          // this thread stages rows sr and sr+16
    int sjA = j0 + sr;
    int sjB = sjA + 16;
    int sbA = sjA / NN_SZ, snA = sjA - sbA*NN_SZ;
    int sbB = sjB / NN_SZ, snB = sjB - sbB*NN_SZ;   // block may straddle batch
    size_t rbaseA = ((size_t)(sbA*T_WIN)*NN_SZ + snA)*64 + c4*4;
    size_t rbaseB = ((size_t)(sbB*T_WIN)*NN_SZ + snB)*64 + c4*4;
    const size_t tstep = (size_t)NN_SZ*64;
    float sc2v[4], sh2v[4];
    #pragma unroll
    for (int q = 0; q < 4; q++){
        int f = c4*4 + q;
        float mean = gsum2[f]*(1.0f/(float)N_NODES);
        float var  = fmaxf(gsq2[f]*(1.0f/(float)N_NODES) - mean*mean, 0.f);
        float sc_  = g2bn[f]*rsqrtf(var + BN_EPS);
        sc2v[q] = sc_; sh2v[q] = be2[f] - mean*sc_;
    }

    float c1r[2][4], c2r[2][4], h2r[2][4];
    #pragma unroll
    for (int tle = 0; tle < 2; tle++)
        #pragma unroll
        for (int i = 0; i < 4; i++){ c1r[tle][i] = 0.f; c2r[tle][i] = 0.f; h2r[tle][i] = 0.f; }

    float bi1 = b1c[u], bf1 = b1c[64+u], bg1 = b1c[128+u], bo1 = b1c[192+u];
    float bi2 = b2c[u], bf2 = b2c[64+u], bg2 = b2c[128+u], bo2 = b2c[192+u];

    {
        half4 v0A = *(const half4*)&h1H[rbaseA];
        half4 g4A = *(const half4*)&g2H[rbaseA];
        half4 v0B = *(const half4*)&h1H[rbaseB];
        half4 g4B = *(const half4*)&g2H[rbaseB];
        half4 v1A, v1B;
        #pragma unroll
        for (int q = 0; q < 4; q++){
            v1A[q] = (_Float16)((float)g4A[q]*sc2v[q] + sh2v[q]);
            v1B[q] = (_Float16)((float)g4B[q]*sc2v[q] + sh2v[q]);
        }
        *(half4*)&X1h[sr*X1S + c4*4]             = v0A;
        *(half4*)&X1h[sr*X1S + 64 + c4*4]        = v1A;
        *(half4*)&X1h[sr*X1S + 128 + c4*4]       = (half4){0,0,0,0};
        *(half4*)&X1h[(sr+16)*X1S + c4*4]        = v0B;
        *(half4*)&X1h[(sr+16)*X1S + 64 + c4*4]   = v1B;
        *(half4*)&X1h[(sr+16)*X1S + 128 + c4*4]  = (half4){0,0,0,0};
    }
    __syncthreads();

    for (int t = 0; t < T_WIN; t++){
        half4 nv0A, ng4A, nv0B, ng4B;
        if (t < T_WIN-1){
            size_t rbA = rbaseA + (size_t)(t+1)*tstep;
            size_t rbB = rbaseB + (size_t)(t+1)*tstep;
            nv0A = *(const half4*)&h1H[rbA];
            ng4A = *(const half4*)&g2H[rbA];
            nv0B = *(const half4*)&h1H[rbB];
            ng4B = *(const half4*)&g2H[rbB];
        }

        // ---- phase 1: gates1 = X1 @ W1^T, K=192, 2 row-tiles per B-frag ----
        f32x4 acc[2][4];
        #pragma unroll
        for (int tle = 0; tle < 2; tle++)
            #pragma unroll
            for (int g = 0; g < 4; g++) acc[tle][g] = (f32x4){0.f,0.f,0.f,0.f};
        #pragma unroll
        for (int kt = 0; kt < 6; kt++){
            half8 a0 = *(const half8*)&X1h[l16*X1S + kt*32 + quad*8];
            half8 a1 = *(const half8*)&X1h[(l16+16)*X1S + kt*32 + quad*8];
            #pragma unroll
            for (int g = 0; g < 4; g++){
                half8 b = *(const half8*)&W1F[(size_t)(kt*256 + 64*g + u)*32 + quad*8];
                acc[0][g] = __builtin_amdgcn_mfma_f32_16x16x32_f16(a0, b, acc[0][g], 0, 0, 0);
                acc[1][g] = __builtin_amdgcn_mfma_f32_16x16x32_f16(a1, b, acc[1][g], 0, 0, 0);
            }
        }
        lds_barrier();   // LDS-only drain: weight/prefetch loads stay in flight

        // ---- cell update 1 (both tiles) + stage X2 + commit t+1 X1 ----
        #pragma unroll
        for (int tle = 0; tle < 2; tle++){
            #pragma unroll
            for (int r = 0; r < 4; r++){
                int rowl = quad*4 + r + 16*tle;
                float gi = acc[tle][0][r] + bi1;
                float gf = acc[tle][1][r] + bf1;
                float gg = acc[tle][2][r] + bg1;
                float go = acc[tle][3][r] + bo1;
                float cn = fsig(gf)*c1r[tle][r] + fsig(gi)*ftanh(gg);
                float hn = fsig(go)*ftanh(cn);
                c1r[tle][r] = cn;
                X2h[rowl*X2S + u]      = (_Float16)hn;
                X2h[rowl*X2S + 64 + u] = (_Float16)h2r[tle][r];
                X1h[rowl*X1S + 128 + u] = (_Float16)hn;
                if (t == T_WIN-1) h1s[(size_t)(j0 + rowl)*64 + u] = hn;
            }
        }
        if (t < T_WIN-1){
            half4 v1A, v1B;
            #pragma unroll
            for (int q = 0; q < 4; q++){
                v1A[q] = (_Float16)((float)ng4A[q]*sc2v[q] + sh2v[q]);
                v1B[q] = (_Float16)((float)ng4B[q]*sc2v[q] + sh2v[q]);
            }
            *(half4*)&X1h[sr*X1S + c4*4]            = nv0A;
            *(half4*)&X1h[sr*X1S + 64 + c4*4]       = v1A;
            *(half4*)&X1h[(sr+16)*X1S + c4*4]       = nv0B;
            *(half4*)&X1h[(sr+16)*X1S + 64 + c4*4]  = v1B;
        }
        lds_barrier();

        // ---- phase 2: gates2 = X2 @ W2^T, K=128 ----
        f32x4 acc2[2][4];
        #pragma unroll
        for (int tle = 0; tle < 2; tle++)
            #pragma unroll
            for (int g = 0; g < 4; g++) acc2[tle][g] = (f32x4){0.f,0.f,0.f,0.f};
        #pragma unroll
        for (int kt = 0; kt < 4; kt++){
            half8 a0 = *(const half8*)&X2h[l16*X2S + kt*32 + quad*8];
            half8 a1 = *(const half8*)&X2h[(l16+16)*X2S + kt*32 + quad*8];
            #pragma unroll
            for (int g = 0; g < 4; g++){
                half8 b = *(const half8*)&W2F[(size_t)(kt*256 + 64*g + u)*32 + quad*8];
                acc2[0][g] = __builtin_amdgcn_mfma_f32_16x16x32_f16(a0, b, acc2[0][g], 0, 0, 0);
                acc2[1][g] = __builtin_amdgcn_mfma_f32_16x16x32_f16(a1, b, acc2[1][g], 0, 0, 0);
            }
        }

        // ---- cell update 2 (both tiles) ----
        #pragma unroll
        for (int tle = 0; tle < 2; tle++){
            #pragma unroll
            for (int r = 0; r < 4; r++){
                int rowl = quad*4 + r + 16*tle;
                float gi = acc2[tle][0][r] + bi2;
                float gf = acc2[tle][1][r] + bf2;
                float gg = acc2[tle][2][r] + bg2;
                float go = acc2[tle][3][r] + bo2;
                float cn = fsig(gf)*c2r[tle][r] + fsig(gi)*ftanh(gg);
                float hn = fsig(go)*ftanh(cn);
                c2r[tle][r] = cn;
                h2r[tle][r] = hn;
                if (t == T_WIN-1) h2s[(size_t)(j0 + rowl)*64 + u] = hn;
            }
        }
    }
}

// ---------- FC head ----------
__global__ __launch_bounds__(256) void fc_head(
        const float* __restrict__ h1s, const float* __restrict__ h2s,
        const float* __restrict__ inner, const float* __restrict__ x,
        const float* __restrict__ fc1_w, const float* __restrict__ fc1_b,
        const float* __restrict__ fc3_w, const float* __restrict__ fc3_b,
        float* __restrict__ out){
    __shared__ float zsm[4][226];
    int wv = threadIdx.x >> 6;
    int f  = threadIdx.x & 63;
    int j  = blockIdx.x*4 + wv;
    int b = j / NN_SZ, n = j - b*NN_SZ;
    for (int k = f; k < 225; k += 64){
        float v;
        if (k < 64)        v = h1s[j*64 + k];
        else if (k < 128)  v = h2s[j*64 + (k-64)];
        else if (k == 128) v = inner[j];
        else {
            int kk = k - 129;
            int w_ = kk >> 3, ff = kk & 7;
            v = x[((b*T_WIN + w_)*NN_SZ + n)*FIN + ff];
        }
        zsm[wv][k] = v;
    }
    __syncthreads();
    float acc = fc1_b[f];
    for (int k = 0; k < 225; k++) acc += zsm[wv][k]*fc1_w[k*64 + f];
    float p = fmaxf(acc, 0.f) * fc3_w[f];
    #pragma unroll
    for (int off = 32; off > 0; off >>= 1) p += __shfl_down(p, off, 64);
    if (f == 0) out[j] = fmaxf(p + fc3_b[0], 0.f);
}

extern "C" void kernel_launch(void* const* d_in, const int* in_sizes, int n_in,
                              void* d_out, int out_size, void* d_ws, size_t ws_size,
                              hipStream_t stream){
    const int*   adj  = (const int*)d_in[0];
    const int*   row  = adj;
    const int*   col  = adj + EDGES;
    const float* aw   = (const float*)d_in[1];
    const float* x    = (const float*)d_in[2];
    const float* inner= (const float*)d_in[3];
    const float* W1   = (const float*)d_in[4];
    const float* b1   = (const float*)d_in[5];
    const float* W2   = (const float*)d_in[6];
    const float* b2   = (const float*)d_in[7];
    const float* g1   = (const float*)d_in[8];
    const float* be1  = (const float*)d_in[9];
    const float* g2   = (const float*)d_in[10];
    const float* be2  = (const float*)d_in[11];
    const float* Wih1 = (const float*)d_in[12];
    const float* Whh1 = (const float*)d_in[13];
    const float* bih1 = (const float*)d_in[14];
    const float* bhh1 = (const float*)d_in[15];
    const float* Wih2 = (const float*)d_in[16];
    const float* Whh2 = (const float*)d_in[17];
    const float* bih2 = (const float*)d_in[18];
    const float* bhh2 = (const float*)d_in[19];
    const float* fc1w = (const float*)d_in[20];
    const float* fc1b = (const float*)d_in[21];
    const float* fc3w = (const float*)d_in[22];
    const float* fc3b = (const float*)d_in[23];
    float* out = (float*)d_out;

    float* ws = (float*)d_ws;
    const size_t NB = (size_t)N_NODES*64;            // 12,288,000 floats
    float* bufX = ws;                                 // blockbase -> hlinH -> LSTM outs + W
    float* bufY = ws + NB;                            // rec -> gcnA1 (fp32) -> g2H (f16)
    float* bufZ = ws + 2*NB;                          // h1H (f16) + ax
    int2*  edge_s  = (int2*)(ws + 3*NB);              // E int2
    float* degdis  = ws + 3*NB + (size_t)2*EDGES;     // N (dis)
    float* gsum    = degdis + N_NODES;                // 64
    float* gsq     = gsum + 64;                       // 64
    float* gsum2   = gsq + 64;                        // 64
    float* gsq2    = gsum2 + 64;                      // 64
    unsigned* gcount = (unsigned*)(gsq2 + 64);        // NBKT
    int* gbase   = (int*)(gcount + NBKT);             // NBKT+1
    int* offsets = gbase + (NBKT + 2);                // N+1

    // preprocessing aliases (dead before their buffers' later users)
    int* blockbase = (int*)bufX;                      // NBLKA*NBKT ints (768 KB)
    int2* rec      = (int2*)bufY;                     // E int2 (16 MB)

    // phase-1 aliases
    float* hlinH = bufX;                              // N*32 floats (f16 pairs)
    _Float16* h1H = (_Float16*)bufZ;                  // N*64 f16
    float* ax    = bufZ + (size_t)N_NODES*32 + 64;    // N*8 fp32
    float* gcnA1 = bufY;                              // N*64 fp32
    float* g2Hf  = bufY;                              // N*32 floats (f16 pairs)

    // LSTM-phase aliases into bufX (hlinH dead after gather2h)
    float* h1s = bufX;
    float* h2s = bufX + (size_t)BN_ROWS*64;
    _Float16* W1F = (_Float16*)(bufX + (size_t)4*BN_ROWS*64);
    _Float16* W2F = W1F + 6*256*32;
    float* b1c = (float*)(W2F + 4*256*32);
    float* b2c = b1c + 256;

    // ---- edge preprocessing: LDS-privatized two-level counting sort ----
    hipMemsetAsync(gcount, 0, NBKT*sizeof(unsigned), stream);
    hipMemsetAsync(gsum, 0, 256*sizeof(float), stream);   // gsum/gsq/gsum2/gsq2
    hist_coarse   <<<NBLKA, 256, 0, stream>>>(col, gcount, blockbase);
    scan_bkt      <<<1, 1024, 0, stream>>>(gcount, gbase, offsets);
    scatter_bucket<<<NBLKA, 256, 0, stream>>>(row, col, aw, blockbase, gbase, rec);
    bucket_deg    <<<NBKT, 256, 0, stream>>>(rec, gbase, degdis);
    bucket_csr    <<<NBKT, 256, 0, stream>>>(rec, gbase, degdis, edge_s, offsets);

    // ---- GCN layer 1 (node-parallel, known-good) ----
    aggx_k<<<N_NODES/32, 256, 0, stream>>>(offsets, edge_s, degdis, x, ax);
    lin1b_stats<<<1024, 256, 0, stream>>>(ax, W1, b1, gcnA1, gsum, gsq);

    // ---- fused BN1(inline) + layer-2 linear ----
    lin2_bn<<<N_NODES/L2ROWS, 128, 0, stream>>>(gcnA1, gsum, gsq, g1, be1, W2, h1H, hlinH);

    // ---- GCN layer 2 (one-shot grid for max MLP) + separate f16 stats pass ----
    gather2h<<<N_NODES/8, 256, 0, stream>>>(offsets, edge_s, degdis, hlinH, b2, g2Hf);
    stats2h<<<1024, 256, 0, stream>>>(g2Hf, gsum2, gsq2);

    // ---- fused 12-step LSTM (32 rows/block, raw LDS-only barriers) ----
    prep_weights<<<(6*256*32 + 4*256*32 + 512 + 255)/256, 256, 0, stream>>>(
        Wih1, Whh1, bih1, bhh1, Wih2, Whh2, bih2, bhh2, W1F, W2F, b1c, b2c);
    lstm_fused<<<BN_ROWS/32, 256, 0, stream>>>(h1H, (const _Float16*)g2Hf,
                                               gsum2, gsq2, g2, be2,
                                               W1F, W2F, b1c, b2c, h1s, h2s);

    // ---- FC head ----
    fc_head<<<BN_ROWS/4, 256, 0, stream>>>(h1s, h2s, inner, x, fc1w, fc1b, fc3w, fc3b, out);
}

// Round 12
// 486.989 us; speedup vs baseline: 1.0693x; 1.0693x over previous
//
#include <hip/hip_runtime.h>
#include <math.h>

#define N_NODES 192000
#define EDGES   2000000
#define HID     64
#define BN_ROWS 16000   // B*NN
#define T_WIN   12
#define B_SZ    8
#define NN_SZ   2000
#define FIN     8
#define BN_EPS  1e-5f

// two-level bucket sort params: bucket = col >> 8 (256 nodes/bucket)
#define NBKT    750
#define NBLKA   256
#define ACHUNK  7824     // 256*7824 = 2,002,944 >= EDGES, divisible by 4
#define BKT_CAP 5120     // mean bucket = 2667, +47 sigma headroom

typedef _Float16 f16x2 __attribute__((ext_vector_type(2)));
typedef _Float16 half4 __attribute__((ext_vector_type(4)));
typedef _Float16 half8 __attribute__((ext_vector_type(8)));
typedef float    f32x4 __attribute__((ext_vector_type(4)));
union F16x2U { float f; f16x2 h; };

// fast sigmoid/tanh: v_exp_f32 + v_rcp_f32 (~1 ulp; f16 inputs dominate error)
__device__ __forceinline__ float frcp(float x){
#if __has_builtin(__builtin_amdgcn_rcpf)
    return __builtin_amdgcn_rcpf(x);
#else
    return 1.0f/x;
#endif
}
__device__ __forceinline__ float fsig(float x){ return frcp(1.0f + __expf(-x)); }
__device__ __forceinline__ float ftanh(float x){ return fmaf(2.0f, fsig(2.0f*x), -1.0f); }

__device__ __forceinline__ float packf16(float a, float b){
    F16x2U u; u.h[0] = (_Float16)a; u.h[1] = (_Float16)b; return u.f;
}

// ---------- pass A: per-block LDS histogram over coarse buckets ----------
__global__ __launch_bounds__(256) void hist_coarse(
        const int* __restrict__ col, unsigned* __restrict__ gcount,
        int* __restrict__ blockbase){
    __shared__ unsigned bh[NBKT];
    int bl = blockIdx.x, tid = threadIdx.x;
    for (int i = tid; i < NBKT; i += 256) bh[i] = 0u;
    __syncthreads();
    int e0 = bl*ACHUNK;
    int e1 = e0 + ACHUNK; if (e1 > EDGES) e1 = EDGES;
    for (int e = e0 + tid*4; e < e1; e += 1024){
        int4 c4 = *(const int4*)&col[e];
        atomicAdd(&bh[((unsigned)c4.x) >> 8], 1u);
        atomicAdd(&bh[((unsigned)c4.y) >> 8], 1u);
        atomicAdd(&bh[((unsigned)c4.z) >> 8], 1u);
        atomicAdd(&bh[((unsigned)c4.w) >> 8], 1u);
    }
    __syncthreads();
    for (int i = tid; i < NBKT; i += 256)
        blockbase[bl*NBKT + i] = (int)atomicAdd(&gcount[i], bh[i]);
}

// ---------- scan of 750 bucket totals ----------
__global__ __launch_bounds__(1024) void scan_bkt(
        const unsigned* __restrict__ gcount, int* __restrict__ gbase,
        int* __restrict__ offsets){
    __shared__ int sm[1024];
    int tid = threadIdx.x;
    int v = (tid < NBKT) ? (int)gcount[tid] : 0;
    sm[tid] = v;
    __syncthreads();
    #pragma unroll
    for (int off = 1; off < 1024; off <<= 1){
        int t = (tid >= off) ? sm[tid - off] : 0;
        __syncthreads();
        sm[tid] += t;
        __syncthreads();
    }
    if (tid < NBKT) gbase[tid] = sm[tid] - v;
    if (tid == NBKT) gbase[NBKT] = EDGES;
    if (tid == NBKT+1) offsets[N_NODES] = EDGES;
}

// ---------- pass B: scatter edges into bucket regions (LDS cursors) ----------
__global__ __launch_bounds__(256) void scatter_bucket(
        const int* __restrict__ row, const int* __restrict__ col,
        const float* __restrict__ w, const int* __restrict__ blockbase,
        const int* __restrict__ gbase, int2* __restrict__ rec){
    __shared__ unsigned cur[NBKT];
    int bl = blockIdx.x, tid = threadIdx.x;
    for (int i = tid; i < NBKT; i += 256)
        cur[i] = (unsigned)(gbase[i] + blockbase[bl*NBKT + i]);
    __syncthreads();
    int e0 = bl*ACHUNK;
    int e1 = e0 + ACHUNK; if (e1 > EDGES) e1 = EDGES;
    for (int e = e0 + tid*4; e < e1; e += 1024){
        int4 r4 = *(const int4*)&row[e];
        int4 c4 = *(const int4*)&col[e];
        float4 w4 = *(const float4*)&w[e];
        int cc[4] = {c4.x, c4.y, c4.z, c4.w};
        int rr[4] = {r4.x, r4.y, r4.z, r4.w};
        float wf[4] = {w4.x, w4.y, w4.z, w4.w};
        #pragma unroll
        for (int q = 0; q < 4; q++){
            int c = cc[q];
            unsigned wfix = (unsigned)(wf[q]*16777216.0f + 0.5f);
            if (wfix > 0xFFFFFFu) wfix = 0xFFFFFFu;
            unsigned p = atomicAdd(&cur[((unsigned)c) >> 8], 1u);
            int2 rv; rv.x = rr[q];
            rv.y = (int)((((unsigned)(c & 255)) << 24) | wfix);
            rec[p] = rv;
        }
    }
}

// ---------- per-bucket weighted degree -> dis, before CSR build ----------
__global__ __launch_bounds__(256) void bucket_deg(
        const int2* __restrict__ rec, const int* __restrict__ gbase,
        float* __restrict__ dis){
    __shared__ unsigned wsum[256];
    int b = blockIdx.x, tid = threadIdx.x;
    wsum[tid] = 0u;
    __syncthreads();
    int k0 = gbase[b], k1 = gbase[b+1];
    for (int i = k0 + tid; i < k1; i += 256){
        int2 r = rec[i];
        atomicAdd(&wsum[((unsigned)r.y) >> 24], ((unsigned)r.y) & 0xFFFFFFu);
    }
    __syncthreads();
    float deg = (float)wsum[tid] * (1.0f/16777216.0f);
    dis[(b<<8) + tid] = rsqrtf(deg + 1.0f);   // + self-loop weight
}

// ---------- pass C: per-bucket exact CSR build, all in LDS ----------
// edge_s.x packs clow<<24 | row; edge_s.y = dis[r]*w*dis[c] fully folded.
__global__ __launch_bounds__(256) void bucket_csr(
        const int2* __restrict__ rec, const int* __restrict__ gbase,
        const float* __restrict__ dis,
        int2* __restrict__ edge_s, int* __restrict__ offsets){
    __shared__ int2 S[BKT_CAP];
    __shared__ unsigned cnt[256];
    __shared__ unsigned cur[256];
    __shared__ float dloc[256];
    int b = blockIdx.x, tid = threadIdx.x;
    int k0 = gbase[b], k1 = gbase[b+1];
    int n = k1 - k0;
    cnt[tid] = 0u;
    dloc[tid] = dis[(b<<8) + tid];
    __syncthreads();
    bool staged = (n <= BKT_CAP);
    for (int i = tid; i < n; i += 256){
        int2 r = rec[k0 + i];
        if (staged) S[i] = r;
        atomicAdd(&cnt[((unsigned)r.y) >> 24], 1u);
    }
    __syncthreads();
    unsigned v = cnt[tid];
    #pragma unroll
    for (int off = 1; off < 256; off <<= 1){
        unsigned t = (tid >= off) ? cnt[tid - off] : 0u;
        __syncthreads();
        cnt[tid] += t;
        __syncthreads();
    }
    unsigned excl = cnt[tid] - v;
    cur[tid] = excl;
    offsets[(b<<8) + tid] = k0 + (int)excl;
    __syncthreads();
    for (int i = tid; i < n; i += 256){
        int2 r = staged ? S[i] : rec[k0 + i];
        unsigned clow = ((unsigned)r.y) >> 24;
        unsigned wfix = ((unsigned)r.y) & 0xFFFFFFu;
        float sv = (float)wfix * (1.0f/16777216.0f) * dloc[clow];
        sv = dis[r.x] * sv;
        unsigned p = atomicAdd(&cur[clow], 1u);
        int2 o; o.x = (int)((clow << 24) | (unsigned)r.x); o.y = __float_as_int(sv);
        edge_s[k0 + (int)p] = o;
    }
}

// ---------- layer-1 aggregation, node-parallel (known-good) ----------
// R17-R19 lesson: edge-parallel LDS-atomic variants all ~90us; this form ~40us.
__global__ __launch_bounds__(256) void aggx_k(
        const int* __restrict__ offsets, const int2* __restrict__ edge_s,
        const float* __restrict__ dis, const float* __restrict__ x,
        float* __restrict__ ax){
    int g   = blockIdx.x*32 + (threadIdx.x >> 3);
    int sub = threadIdx.x & 7;
    float d = dis[g];
    float acc = x[(size_t)g*8 + sub]*d*d;
    int k  = offsets[g];
    int k1 = offsets[g+1];
    for (; k+4 <= k1; k += 4){
        int2 e0 = edge_s[k], e1 = edge_s[k+1], e2 = edge_s[k+2], e3 = edge_s[k+3];
        float v0 = x[(size_t)(e0.x & 0xFFFFFF)*8 + sub];
        float v1 = x[(size_t)(e1.x & 0xFFFFFF)*8 + sub];
        float v2 = x[(size_t)(e2.x & 0xFFFFFF)*8 + sub];
        float v3 = x[(size_t)(e3.x & 0xFFFFFF)*8 + sub];
        acc += v0*__int_as_float(e0.y);
        acc += v1*__int_as_float(e1.y);
        acc += v2*__int_as_float(e2.y);
        acc += v3*__int_as_float(e3.y);
    }
    for (; k < k1; k++){
        int2 e0 = edge_s[k];
        acc += x[(size_t)(e0.x & 0xFFFFFF)*8 + sub]*__int_as_float(e0.y);
    }
    ax[(size_t)g*8 + sub] = acc;
}

// ---------- BN1 stats only (R24: gcnA1 49MB intermediate eliminated; ----------
// lin2_bn recomputes relu(ax@W1+b1) from ax (6MB) with identical fp32 ops)
__global__ __launch_bounds__(256) void lin1b_stats(
        const float* __restrict__ ax, const float* __restrict__ W1,
        const float* __restrict__ b1,
        float* __restrict__ gsum, float* __restrict__ gsq){
    __shared__ float Ws[512];
    for (int i = threadIdx.x; i < 512; i += 256) Ws[i] = W1[i];
    __syncthreads();
    int f = threadIdx.x & 63;
    float wc[8];
    #pragma unroll
    for (int q = 0; q < 8; q++) wc[q] = Ws[q*64 + f];
    float bb = b1[f];
    float s = 0.f, s2 = 0.f;
    int stride = gridDim.x*blockDim.x;   // multiple of 64
    for (int idx = blockIdx.x*blockDim.x + threadIdx.x; idx < N_NODES*64; idx += stride){
        int j = idx >> 6;
        const float* ar = ax + (size_t)j*8;
        float acc = bb;
        #pragma unroll
        for (int q = 0; q < 8; q++) acc += ar[q]*wc[q];
        float v = fmaxf(acc, 0.f);
        s += v; s2 += v*v;
    }
    __shared__ float s1m[256], s2m[256];
    s1m[threadIdx.x] = s; s2m[threadIdx.x] = s2;
    __syncthreads();
    if (threadIdx.x < 64){
        float t1 = s1m[threadIdx.x]+s1m[threadIdx.x+64]+s1m[threadIdx.x+128]+s1m[threadIdx.x+192];
        float t2 = s2m[threadIdx.x]+s2m[threadIdx.x+64]+s2m[threadIdx.x+128]+s2m[threadIdx.x+192];
        atomicAdd(&gsum[threadIdx.x], t1);
        atomicAdd(&gsq[threadIdx.x], t2);
    }
}

// ---------- lin2_bn: recompute gcn1 from ax, then h1H + hlinH ----------
// Same fp32 expression/order as lin1b_stats (acc = b1 + sum_q ar[q]*W1col)
// -> bit-identical values; saves 49MB write + 49MB read of gcnA1.
#define L2ROWS 128
#define XS2    132
__global__ __launch_bounds__(128) void lin2_bn(
        const float* __restrict__ ax, const float* __restrict__ W1,
        const float* __restrict__ b1,
        const float* __restrict__ gsum, const float* __restrict__ gsq,
        const float* __restrict__ g1, const float* __restrict__ be1,
        const float* __restrict__ W2,
        _Float16* __restrict__ h1H, float* __restrict__ hlinH){
    __shared__ float Ws[64*64];
    __shared__ float W1s[512];
    __shared__ float b1s[64];
    __shared__ float xsT[64*XS2];
    int tid = threadIdx.x;
    int r0 = blockIdx.x * L2ROWS;

    for (int i = tid; i < 1024; i += 128)
        *(float4*)&Ws[i*4] = *(const float4*)&W2[i*4];
    for (int i = tid; i < 512; i += 128) W1s[i] = W1[i];
    if (tid < 64) b1s[tid] = b1[tid];

    int k4 = tid & 15;
    int rb = tid >> 4;
    float scv[4], shv[4];
    #pragma unroll
    for (int q = 0; q < 4; q++){
        int f = k4*4 + q;
        float mean = gsum[f]*(1.0f/(float)N_NODES);
        float var  = fmaxf(gsq[f]*(1.0f/(float)N_NODES) - mean*mean, 0.f);
        float sc_  = g1[f]*rsqrtf(var + BN_EPS);
        scv[q] = sc_; shv[q] = be1[f] - mean*sc_;
    }
    __syncthreads();   // W1s/b1s ready

    for (int it = 0; it < 16; it++){
        int r = it*8 + rb;
        const float* arp = &ax[(size_t)(r0+r)*8];
        float4 a0 = *(const float4*)arp;
        float4 a1 = *(const float4*)(arp+4);
        float av[8] = {a0.x,a0.y,a0.z,a0.w,a1.x,a1.y,a1.z,a1.w};
        float4 v;
        #pragma unroll
        for (int q = 0; q < 4; q++){
            int f = k4*4 + q;
            float acc = b1s[f];
            #pragma unroll
            for (int p = 0; p < 8; p++) acc += av[p]*W1s[p*64 + f];
            float relu = fmaxf(acc, 0.f);
            v[q] = relu*scv[q] + shv[q];
        }
        half4 hh;
        hh[0]=(_Float16)v[0]; hh[1]=(_Float16)v[1]; hh[2]=(_Float16)v[2]; hh[3]=(_Float16)v[3];
        *(half4*)&h1H[(size_t)(r0+r)*64 + k4*4] = hh;
        xsT[(k4*4+0)*XS2 + r] = v[0];
        xsT[(k4*4+1)*XS2 + r] = v[1];
        xsT[(k4*4+2)*XS2 + r] = v[2];
        xsT[(k4*4+3)*XS2 + r] = v[3];
    }
    __syncthreads();

    int cg = tid & 7;
    int rg = tid >> 3;
    float acc[8][8];
    #pragma unroll
    for (int i = 0; i < 8; i++)
        #pragma unroll
        for (int j = 0; j < 8; j++) acc[i][j] = 0.f;

    float4 a0 = *(float4*)&xsT[0*XS2 + rg*8];
    float4 a1 = *(float4*)&xsT[0*XS2 + rg*8 + 4];
    float4 w0 = *(float4*)&Ws[0*64 + cg*8];
    float4 w1 = *(float4*)&Ws[0*64 + cg*8 + 4];
    for (int k = 0; k < 64; k++){
        float4 na0, na1, nw0, nw1;
        if (k < 63){
            na0 = *(float4*)&xsT[(k+1)*XS2 + rg*8];
            na1 = *(float4*)&xsT[(k+1)*XS2 + rg*8 + 4];
            nw0 = *(float4*)&Ws[(k+1)*64 + cg*8];
            nw1 = *(float4*)&Ws[(k+1)*64 + cg*8 + 4];
        }
        float ar[8] = {a0.x,a0.y,a0.z,a0.w,a1.x,a1.y,a1.z,a1.w};
        float wcv[8] = {w0.x,w0.y,w0.z,w0.w,w1.x,w1.y,w1.z,w1.w};
        #pragma unroll
        for (int i = 0; i < 8; i++)
            #pragma unroll
            for (int j = 0; j < 8; j++) acc[i][j] += ar[i]*wcv[j];
        a0=na0; a1=na1; w0=nw0; w1=nw1;
    }
    #pragma unroll
    for (int i = 0; i < 8; i++){
        size_t r = (size_t)(r0 + rg*8 + i);
        float4 pk;
        pk.x = packf16(acc[i][0], acc[i][1]);
        pk.y = packf16(acc[i][2], acc[i][3]);
        pk.z = packf16(acc[i][4], acc[i][5]);
        pk.w = packf16(acc[i][6], acc[i][7]);
        *(float4*)&hlinH[r*32 + cg*4] = pk;
    }
}

// ---------- layer-2 gather over packed f16 rows, one-shot grid (max MLP) ----------
__global__ __launch_bounds__(256) void gather2h(
        const int* __restrict__ offsets, const int2* __restrict__ edge_s,
        const float* __restrict__ dis, const float* __restrict__ hlinH,
        const float* __restrict__ bias, float* __restrict__ g2Hf){
    int j = blockIdx.x*8 + (threadIdx.x >> 5);
    int p = threadIdx.x & 31;
    float d = dis[j];
    float dd = d*d;
    F16x2U u; u.f = hlinH[(size_t)j*32 + p];
    float ax = (float)u.h[0]*dd;
    float ay = (float)u.h[1]*dd;
    int k  = offsets[j];
    int k1 = offsets[j+1];
    for (; k+4 <= k1; k += 4){
        int2 e0 = edge_s[k], e1 = edge_s[k+1], e2 = edge_s[k+2], e3 = edge_s[k+3];
        F16x2U a, b, c, e;
        a.f = hlinH[(size_t)(e0.x & 0xFFFFFF)*32 + p];
        b.f = hlinH[(size_t)(e1.x & 0xFFFFFF)*32 + p];
        c.f = hlinH[(size_t)(e2.x & 0xFFFFFF)*32 + p];
        e.f = hlinH[(size_t)(e3.x & 0xFFFFFF)*32 + p];
        float n0 = __int_as_float(e0.y), n1 = __int_as_float(e1.y);
        float n2 = __int_as_float(e2.y), n3 = __int_as_float(e3.y);
        ax += (float)a.h[0]*n0; ay += (float)a.h[1]*n0;
        ax += (float)b.h[0]*n1; ay += (float)b.h[1]*n1;
        ax += (float)c.h[0]*n2; ay += (float)c.h[1]*n2;
        ax += (float)e.h[0]*n3; ay += (float)e.h[1]*n3;
    }
    for (; k < k1; k++){
        int2 e0 = edge_s[k];
        F16x2U a; a.f = hlinH[(size_t)(e0.x & 0xFFFFFF)*32 + p];
        float n0 = __int_as_float(e0.y);
        ax += (float)a.h[0]*n0; ay += (float)a.h[1]*n0;
    }
    float2 bv = *(const float2*)&bias[2*p];
    float vx = fmaxf(ax + bv.x, 0.f);
    float vy = fmaxf(ay + bv.y, 0.f);
    F16x2U o; o.h[0] = (_Float16)vx; o.h[1] = (_Float16)vy;
    g2Hf[(size_t)j*32 + p] = o.f;
}

// ---------- BN2 stats over f16 output (12.3 MB pass) ----------
__global__ __launch_bounds__(256) void stats2h(
        const float* __restrict__ g2Hf, float* __restrict__ gsum2, float* __restrict__ gsq2){
    int p = threadIdx.x & 31;
    float s0 = 0.f, s1 = 0.f, q0 = 0.f, q1 = 0.f;
    int stride = gridDim.x*blockDim.x;   // multiple of 32 -> p constant
    for (int idx = blockIdx.x*blockDim.x + threadIdx.x; idx < N_NODES*32; idx += stride){
        F16x2U u; u.f = g2Hf[idx];
        float vx = (float)u.h[0], vy = (float)u.h[1];
        s0 += vx; q0 += vx*vx;
        s1 += vy; q1 += vy*vy;
    }
    __shared__ float sb[128];
    if (threadIdx.x < 128) sb[threadIdx.x] = 0.f;
    __syncthreads();
    atomicAdd(&sb[2*p],      s0);
    atomicAdd(&sb[2*p+1],    s1);
    atomicAdd(&sb[64+2*p],   q0);
    atomicAdd(&sb[64+2*p+1], q1);
    __syncthreads();
    if (threadIdx.x < 64){
        atomicAdd(&gsum2[threadIdx.x], sb[threadIdx.x]);
        atomicAdd(&gsq2[threadIdx.x],  sb[64+threadIdx.x]);
    }
}

// ---------- LSTM weight prep: B-fragment layout [K/32][256][32] f16 ----------
__global__ void prep_weights(const float* __restrict__ Wih1, const float* __restrict__ Whh1,
                             const float* __restrict__ bih1, const float* __restrict__ bhh1,
                             const float* __restrict__ Wih2, const float* __restrict__ Whh2,
                             const float* __restrict__ bih2, const float* __restrict__ bhh2,
                             _Float16* W1F, _Float16* W2F, float* b1c, float* b2c){
    int idx = blockIdx.x*blockDim.x + threadIdx.x;
    if (idx < 6*256*32){
        int kt = idx >> 13;
        int rem = idx & 8191;
        int n = rem >> 5, kin = rem & 31;
        int k = kt*32 + kin;
        float v = (k < 128) ? Wih1[n*128 + k] : Whh1[n*64 + (k-128)];
        W1F[idx] = (_Float16)v;
    }
    int i2 = idx - 6*256*32;
    if (i2 >= 0 && i2 < 4*256*32){
        int kt = i2 >> 13;
        int rem = i2 & 8191;
        int n = rem >> 5, kin = rem & 31;
        int k = kt*32 + kin;
        float v = (k < 64) ? Wih2[n*64 + k] : Whh2[n*64 + (k-64)];
        W2F[i2] = (_Float16)v;
    }
    int i3 = idx - (6*256*32 + 4*256*32);
    if (i3 >= 0 && i3 < 256) b1c[i3] = bih1[i3] + bhh1[i3];
    int i4 = i3 - 256;
    if (i4 >= 0 && i4 < 256) b2c[i4] = bih2[i4] + bhh2[i4];
}

// ---------- fused 12-step LSTM1+LSTM2, MFMA 16x16x32 f16, 32 rows/block ----------
// R21 known-good form VERBATIM (77.5us, VGPR 196, 2 __syncthreads/step).
// R22 (gate-split, weights-in-reg) was null; R23 (raw LDS barrier +
// sched_barrier) regressed to 106 by wrecking compiler scheduling. This
// kernel is at its structural floor for source-level tools -- do not touch.
#define X1S 200   // halves/row, 400 B
#define X2S 136   // halves/row, 272 B
__global__ __launch_bounds__(256) void lstm_fused(
        const _Float16* __restrict__ h1H, const _Float16* __restrict__ g2H,
        const float* __restrict__ gsum2, const float* __restrict__ gsq2,
        const float* __restrict__ g2bn, const float* __restrict__ be2,
        const _Float16* __restrict__ W1F, const _Float16* __restrict__ W2F,
        const float* __restrict__ b1c, const float* __restrict__ b2c,
        float* __restrict__ h1s, float* __restrict__ h2s){
    __shared__ _Float16 X1h[32*X1S];
    __shared__ _Float16 X2h[32*X2S];
    int tid = threadIdx.x;
    int j0 = blockIdx.x*32;
    int w    = tid >> 6;
    int lane = tid & 63;
    int quad = lane >> 4;
    int l16  = lane & 15;
    int u    = 16*w + l16;

    int c4 = tid & 15;
    int sr = (tid >> 4) & 15;          // this thread stages rows sr and sr+16
    int sjA = j0 + sr;
    int sjB = sjA + 16;
    int sbA = sjA / NN_SZ, snA = sjA - sbA*NN_SZ;
    int sbB = sjB / NN_SZ, snB = sjB - sbB*NN_SZ;   // block may straddle batch
    size_t rbaseA = ((size_t)(sbA*T_WIN)*NN_SZ + snA)*64 + c4*4;
    size_t rbaseB = ((size_t)(sbB*T_WIN)*NN_SZ + snB)*64 + c4*4;
    const size_t tstep = (size_t)NN_SZ*64;
    float sc2v[4], sh2v[4];
    #pragma unroll
    for (int q = 0; q < 4; q++){
        int f = c4*4 + q;
        float mean = gsum2[f]*(1.0f/(float)N_NODES);
        float var  = fmaxf(gsq2[f]*(1.0f/(float)N_NODES) - mean*mean, 0.f);
        float sc_  = g2bn[f]*rsqrtf(var + BN_EPS);
        sc2v[q] = sc_; sh2v[q] = be2[f] - mean*sc_;
    }

    float c1r[2][4], c2r[2][4], h2r[2][4];
    #pragma unroll
    for (int tle = 0; tle < 2; tle++)
        #pragma unroll
        for (int i = 0; i < 4; i++){ c1r[tle][i] = 0.f; c2r[tle][i] = 0.f; h2r[tle][i] = 0.f; }

    float bi1 = b1c[u], bf1 = b1c[64+u], bg1 = b1c[128+u], bo1 = b1c[192+u];
    float bi2 = b2c[u], bf2 = b2c[64+u], bg2 = b2c[128+u], bo2 = b2c[192+u];

    {
        half4 v0A = *(const half4*)&h1H[rbaseA];
        half4 g4A = *(const half4*)&g2H[rbaseA];
        half4 v0B = *(const half4*)&h1H[rbaseB];
        half4 g4B = *(const half4*)&g2H[rbaseB];
        half4 v1A, v1B;
        #pragma unroll
        for (int q = 0; q < 4; q++){
            v1A[q] = (_Float16)((float)g4A[q]*sc2v[q] + sh2v[q]);
            v1B[q] = (_Float16)((float)g4B[q]*sc2v[q] + sh2v[q]);
        }
        *(half4*)&X1h[sr*X1S + c4*4]             = v0A;
        *(half4*)&X1h[sr*X1S + 64 + c4*4]        = v1A;
        *(half4*)&X1h[sr*X1S + 128 + c4*4]       = (half4){0,0,0,0};
        *(half4*)&X1h[(sr+16)*X1S + c4*4]        = v0B;
        *(half4*)&X1h[(sr+16)*X1S + 64 + c4*4]   = v1B;
        *(half4*)&X1h[(sr+16)*X1S + 128 + c4*4]  = (half4){0,0,0,0};
    }
    __syncthreads();

    for (int t = 0; t < T_WIN; t++){
        half4 nv0A, ng4A, nv0B, ng4B;
        if (t < T_WIN-1){
            size_t rbA = rbaseA + (size_t)(t+1)*tstep;
            size_t rbB = rbaseB + (size_t)(t+1)*tstep;
            nv0A = *(const half4*)&h1H[rbA];
            ng4A = *(const half4*)&g2H[rbA];
            nv0B = *(const half4*)&h1H[rbB];
            ng4B = *(const half4*)&g2H[rbB];
        }

        // ---- phase 1: gates1 = X1 @ W1^T, K=192, 2 row-tiles per B-frag ----
        f32x4 acc[2][4];
        #pragma unroll
        for (int tle = 0; tle < 2; tle++)
            #pragma unroll
            for (int g = 0; g < 4; g++) acc[tle][g] = (f32x4){0.f,0.f,0.f,0.f};
        #pragma unroll
        for (int kt = 0; kt < 6; kt++){
            half8 a0 = *(const half8*)&X1h[l16*X1S + kt*32 + quad*8];
            half8 a1 = *(const half8*)&X1h[(l16+16)*X1S + kt*32 + quad*8];
            #pragma unroll
            for (int g = 0; g < 4; g++){
                half8 b = *(const half8*)&W1F[(size_t)(kt*256 + 64*g + u)*32 + quad*8];
                acc[0][g] = __builtin_amdgcn_mfma_f32_16x16x32_f16(a0, b, acc[0][g], 0, 0, 0);
                acc[1][g] = __builtin_amdgcn_mfma_f32_16x16x32_f16(a1, b, acc[1][g], 0, 0, 0);
            }
        }
        __syncthreads();

        // ---- cell update 1 (both tiles) + stage X2 + commit t+1 X1 ----
        #pragma unroll
        for (int tle = 0; tle < 2; tle++){
            #pragma unroll
            for (int r = 0; r < 4; r++){
                int rowl = quad*4 + r + 16*tle;
                float gi = acc[tle][0][r] + bi1;
                float gf = acc[tle][1][r] + bf1;
                float gg = acc[tle][2][r] + bg1;
                float go = acc[tle][3][r] + bo1;
                float cn = fsig(gf)*c1r[tle][r] + fsig(gi)*ftanh(gg);
                float hn = fsig(go)*ftanh(cn);
                c1r[tle][r] = cn;
                X2h[rowl*X2S + u]      = (_Float16)hn;
                X2h[rowl*X2S + 64 + u] = (_Float16)h2r[tle][r];
                X1h[rowl*X1S + 128 + u] = (_Float16)hn;
                if (t == T_WIN-1) h1s[(size_t)(j0 + rowl)*64 + u] = hn;
            }
        }
        if (t < T_WIN-1){
            half4 v1A, v1B;
            #pragma unroll
            for (int q = 0; q < 4; q++){
                v1A[q] = (_Float16)((float)ng4A[q]*sc2v[q] + sh2v[q]);
                v1B[q] = (_Float16)((float)ng4B[q]*sc2v[q] + sh2v[q]);
            }
            *(half4*)&X1h[sr*X1S + c4*4]            = nv0A;
            *(half4*)&X1h[sr*X1S + 64 + c4*4]       = v1A;
            *(half4*)&X1h[(sr+16)*X1S + c4*4]       = nv0B;
            *(half4*)&X1h[(sr+16)*X1S + 64 + c4*4]  = v1B;
        }
        __syncthreads();

        // ---- phase 2: gates2 = X2 @ W2^T, K=128 ----
        f32x4 acc2[2][4];
        #pragma unroll
        for (int tle = 0; tle < 2; tle++)
            #pragma unroll
            for (int g = 0; g < 4; g++) acc2[tle][g] = (f32x4){0.f,0.f,0.f,0.f};
        #pragma unroll
        for (int kt = 0; kt < 4; kt++){
            half8 a0 = *(const half8*)&X2h[l16*X2S + kt*32 + quad*8];
            half8 a1 = *(const half8*)&X2h[(l16+16)*X2S + kt*32 + quad*8];
            #pragma unroll
            for (int g = 0; g < 4; g++){
                half8 b = *(const half8*)&W2F[(size_t)(kt*256 + 64*g + u)*32 + quad*8];
                acc2[0][g] = __builtin_amdgcn_mfma_f32_16x16x32_f16(a0, b, acc2[0][g], 0, 0, 0);
                acc2[1][g] = __builtin_amdgcn_mfma_f32_16x16x32_f16(a1, b, acc2[1][g], 0, 0, 0);
            }
        }

        // ---- cell update 2 (both tiles) ----
        #pragma unroll
        for (int tle = 0; tle < 2; tle++){
            #pragma unroll
            for (int r = 0; r < 4; r++){
                int rowl = quad*4 + r + 16*tle;
                float gi = acc2[tle][0][r] + bi2;
                float gf = acc2[tle][1][r] + bf2;
                float gg = acc2[tle][2][r] + bg2;
                float go = acc2[tle][3][r] + bo2;
                float cn = fsig(gf)*c2r[tle][r] + fsig(gi)*ftanh(gg);
                float hn = fsig(go)*ftanh(cn);
                c2r[tle][r] = cn;
                h2r[tle][r] = hn;
                if (t == T_WIN-1) h2s[(size_t)(j0 + rowl)*64 + u] = hn;
            }
        }
    }
}

// ---------- FC head ----------
__global__ __launch_bounds__(256) void fc_head(
        const float* __restrict__ h1s, const float* __restrict__ h2s,
        const float* __restrict__ inner, const float* __restrict__ x,
        const float* __restrict__ fc1_w, const float* __restrict__ fc1_b,
        const float* __restrict__ fc3_w, const float* __restrict__ fc3_b,
        float* __restrict__ out){
    __shared__ float zsm[4][226];
    int wv = threadIdx.x >> 6;
    int f  = threadIdx.x & 63;
    int j  = blockIdx.x*4 + wv;
    int b = j / NN_SZ, n = j - b*NN_SZ;
    for (int k = f; k < 225; k += 64){
        float v;
        if (k < 64)        v = h1s[j*64 + k];
        else if (k < 128)  v = h2s[j*64 + (k-64)];
        else if (k == 128) v = inner[j];
        else {
            int kk = k - 129;
            int w_ = kk >> 3, ff = kk & 7;
            v = x[((b*T_WIN + w_)*NN_SZ + n)*FIN + ff];
        }
        zsm[wv][k] = v;
    }
    __syncthreads();
    float acc = fc1_b[f];
    for (int k = 0; k < 225; k++) acc += zsm[wv][k]*fc1_w[k*64 + f];
    float p = fmaxf(acc, 0.f) * fc3_w[f];
    #pragma unroll
    for (int off = 32; off > 0; off >>= 1) p += __shfl_down(p, off, 64);
    if (f == 0) out[j] = fmaxf(p + fc3_b[0], 0.f);
}

extern "C" void kernel_launch(void* const* d_in, const int* in_sizes, int n_in,
                              void* d_out, int out_size, void* d_ws, size_t ws_size,
                              hipStream_t stream){
    const int*   adj  = (const int*)d_in[0];
    const int*   row  = adj;
    const int*   col  = adj + EDGES;
    const float* aw   = (const float*)d_in[1];
    const float* x    = (const float*)d_in[2];
    const float* inner= (const float*)d_in[3];
    const float* W1   = (const float*)d_in[4];
    const float* b1   = (const float*)d_in[5];
    const float* W2   = (const float*)d_in[6];
    const float* b2   = (const float*)d_in[7];
    const float* g1   = (const float*)d_in[8];
    const float* be1  = (const float*)d_in[9];
    const float* g2   = (const float*)d_in[10];
    const float* be2  = (const float*)d_in[11];
    const float* Wih1 = (const float*)d_in[12];
    const float* Whh1 = (const float*)d_in[13];
    const float* bih1 = (const float*)d_in[14];
    const float* bhh1 = (const float*)d_in[15];
    const float* Wih2 = (const float*)d_in[16];
    const float* Whh2 = (const float*)d_in[17];
    const float* bih2 = (const float*)d_in[18];
    const float* bhh2 = (const float*)d_in[19];
    const float* fc1w = (const float*)d_in[20];
    const float* fc1b = (const float*)d_in[21];
    const float* fc3w = (const float*)d_in[22];
    const float* fc3b = (const float*)d_in[23];
    float* out = (float*)d_out;

    float* ws = (float*)d_ws;
    const size_t NB = (size_t)N_NODES*64;            // 12,288,000 floats
    float* bufX = ws;                                 // blockbase -> hlinH -> LSTM outs + W
    float* bufY = ws + NB;                            // rec -> g2H (f16)
    float* bufZ = ws + 2*NB;                          // h1H (f16) + ax
    int2*  edge_s  = (int2*)(ws + 3*NB);              // E int2
    float* degdis  = ws + 3*NB + (size_t)2*EDGES;     // N (dis)
    float* gsum    = degdis + N_NODES;                // 64
    float* gsq     = gsum + 64;                       // 64
    float* gsum2   = gsq + 64;                        // 64
    float* gsq2    = gsum2 + 64;                      // 64
    unsigned* gcount = (unsigned*)(gsq2 + 64);        // NBKT
    int* gbase   = (int*)(gcount + NBKT);             // NBKT+1
    int* offsets = gbase + (NBKT + 2);                // N+1

    // preprocessing aliases (dead before their buffers' later users)
    int* blockbase = (int*)bufX;                      // NBLKA*NBKT ints (768 KB)
    int2* rec      = (int2*)bufY;                     // E int2 (16 MB)

    // phase-1 aliases
    float* hlinH = bufX;                              // N*32 floats (f16 pairs)
    _Float16* h1H = (_Float16*)bufZ;                  // N*64 f16
    float* ax    = bufZ + (size_t)N_NODES*32 + 64;    // N*8 fp32
    float* g2Hf  = bufY;                              // N*32 floats (f16 pairs)

    // LSTM-phase aliases into bufX (hlinH dead after gather2h)
    float* h1s = bufX;
    float* h2s = bufX + (size_t)BN_ROWS*64;
    _Float16* W1F = (_Float16*)(bufX + (size_t)4*BN_ROWS*64);
    _Float16* W2F = W1F + 6*256*32;
    float* b1c = (float*)(W2F + 4*256*32);
    float* b2c = b1c + 256;

    // ---- edge preprocessing: LDS-privatized two-level counting sort ----
    hipMemsetAsync(gcount, 0, NBKT*sizeof(unsigned), stream);
    hipMemsetAsync(gsum, 0, 256*sizeof(float), stream);   // gsum/gsq/gsum2/gsq2
    hist_coarse   <<<NBLKA, 256, 0, stream>>>(col, gcount, blockbase);
    scan_bkt      <<<1, 1024, 0, stream>>>(gcount, gbase, offsets);
    scatter_bucket<<<NBLKA, 256, 0, stream>>>(row, col, aw, blockbase, gbase, rec);
    bucket_deg    <<<NBKT, 256, 0, stream>>>(rec, gbase, degdis);
    bucket_csr    <<<NBKT, 256, 0, stream>>>(rec, gbase, degdis, edge_s, offsets);

    // ---- GCN layer 1 (node-parallel, known-good) ----
    aggx_k<<<N_NODES/32, 256, 0, stream>>>(offsets, edge_s, degdis, x, ax);
    lin1b_stats<<<1024, 256, 0, stream>>>(ax, W1, b1, gsum, gsq);

    // ---- BN1 + layer-2 linear, gcn1 recomputed from ax (no 49MB intermediate) ----
    lin2_bn<<<N_NODES/L2ROWS, 128, 0, stream>>>(ax, W1, b1, gsum, gsq, g1, be1, W2, h1H, hlinH);

    // ---- GCN layer 2 (one-shot grid for max MLP) + separate f16 stats pass ----
    gather2h<<<N_NODES/8, 256, 0, stream>>>(offsets, edge_s, degdis, hlinH, b2, g2Hf);
    stats2h<<<1024, 256, 0, stream>>>(g2Hf, gsum2, gsq2);

    // ---- fused 12-step LSTM (32 rows/block, R21 known-good) ----
    prep_weights<<<(6*256*32 + 4*256*32 + 512 + 255)/256, 256, 0, stream>>>(
        Wih1, Whh1, bih1, bhh1, Wih2, Whh2, bih2, bhh2, W1F, W2F, b1c, b2c);
    lstm_fused<<<BN_ROWS/32, 256, 0, stream>>>(h1H, (const _Float16*)g2Hf,
                                               gsum2, gsq2, g2, be2,
                                               W1F, W2F, b1c, b2c, h1s, h2s);

    // ---- FC head ----
    fc_head<<<BN_ROWS/4, 256, 0, stream>>>(h1s, h2s, inner, x, fc1w, fc1b, fc3w, fc3b, out);
}

// Round 13
// 486.800 us; speedup vs baseline: 1.0698x; 1.0004x over previous
//
#include <hip/hip_runtime.h>
#include <math.h>

#define N_NODES 192000
#define EDGES   2000000
#define HID     64
#define BN_ROWS 16000   // B*NN
#define T_WIN   12
#define B_SZ    8
#define NN_SZ   2000
#define FIN     8
#define BN_EPS  1e-5f

// two-level bucket sort params: bucket = col >> 8 (256 nodes/bucket)
#define NBKT    750
#define NBLKA   256
#define ACHUNK  7824     // 256*7824 = 2,002,944 >= EDGES, divisible by 4
#define BKT_CAP 5120     // mean bucket = 2667, +47 sigma headroom

typedef _Float16 f16x2 __attribute__((ext_vector_type(2)));
typedef _Float16 half4 __attribute__((ext_vector_type(4)));
typedef _Float16 half8 __attribute__((ext_vector_type(8)));
typedef float    f32x4 __attribute__((ext_vector_type(4)));
union F16x2U { float f; f16x2 h; };

// fast sigmoid/tanh: v_exp_f32 + v_rcp_f32 (~1 ulp; f16 inputs dominate error)
__device__ __forceinline__ float frcp(float x){
#if __has_builtin(__builtin_amdgcn_rcpf)
    return __builtin_amdgcn_rcpf(x);
#else
    return 1.0f/x;
#endif
}
__device__ __forceinline__ float fsig(float x){ return frcp(1.0f + __expf(-x)); }
__device__ __forceinline__ float ftanh(float x){ return fmaf(2.0f, fsig(2.0f*x), -1.0f); }

__device__ __forceinline__ float packf16(float a, float b){
    F16x2U u; u.h[0] = (_Float16)a; u.h[1] = (_Float16)b; return u.f;
}

// ---------- pass A: per-block LDS histogram over coarse buckets ----------
__global__ __launch_bounds__(256) void hist_coarse(
        const int* __restrict__ col, unsigned* __restrict__ gcount,
        int* __restrict__ blockbase){
    __shared__ unsigned bh[NBKT];
    int bl = blockIdx.x, tid = threadIdx.x;
    for (int i = tid; i < NBKT; i += 256) bh[i] = 0u;
    __syncthreads();
    int e0 = bl*ACHUNK;
    int e1 = e0 + ACHUNK; if (e1 > EDGES) e1 = EDGES;
    for (int e = e0 + tid*4; e < e1; e += 1024){
        int4 c4 = *(const int4*)&col[e];
        atomicAdd(&bh[((unsigned)c4.x) >> 8], 1u);
        atomicAdd(&bh[((unsigned)c4.y) >> 8], 1u);
        atomicAdd(&bh[((unsigned)c4.z) >> 8], 1u);
        atomicAdd(&bh[((unsigned)c4.w) >> 8], 1u);
    }
    __syncthreads();
    for (int i = tid; i < NBKT; i += 256)
        blockbase[bl*NBKT + i] = (int)atomicAdd(&gcount[i], bh[i]);
}

// ---------- scan of 750 bucket totals ----------
__global__ __launch_bounds__(1024) void scan_bkt(
        const unsigned* __restrict__ gcount, int* __restrict__ gbase,
        int* __restrict__ offsets){
    __shared__ int sm[1024];
    int tid = threadIdx.x;
    int v = (tid < NBKT) ? (int)gcount[tid] : 0;
    sm[tid] = v;
    __syncthreads();
    #pragma unroll
    for (int off = 1; off < 1024; off <<= 1){
        int t = (tid >= off) ? sm[tid - off] : 0;
        __syncthreads();
        sm[tid] += t;
        __syncthreads();
    }
    if (tid < NBKT) gbase[tid] = sm[tid] - v;
    if (tid == NBKT) gbase[NBKT] = EDGES;
    if (tid == NBKT+1) offsets[N_NODES] = EDGES;
}

// ---------- pass B: scatter edges into bucket regions (LDS cursors) ----------
__global__ __launch_bounds__(256) void scatter_bucket(
        const int* __restrict__ row, const int* __restrict__ col,
        const float* __restrict__ w, const int* __restrict__ blockbase,
        const int* __restrict__ gbase, int2* __restrict__ rec){
    __shared__ unsigned cur[NBKT];
    int bl = blockIdx.x, tid = threadIdx.x;
    for (int i = tid; i < NBKT; i += 256)
        cur[i] = (unsigned)(gbase[i] + blockbase[bl*NBKT + i]);
    __syncthreads();
    int e0 = bl*ACHUNK;
    int e1 = e0 + ACHUNK; if (e1 > EDGES) e1 = EDGES;
    for (int e = e0 + tid*4; e < e1; e += 1024){
        int4 r4 = *(const int4*)&row[e];
        int4 c4 = *(const int4*)&col[e];
        float4 w4 = *(const float4*)&w[e];
        int cc[4] = {c4.x, c4.y, c4.z, c4.w};
        int rr[4] = {r4.x, r4.y, r4.z, r4.w};
        float wf[4] = {w4.x, w4.y, w4.z, w4.w};
        #pragma unroll
        for (int q = 0; q < 4; q++){
            int c = cc[q];
            unsigned wfix = (unsigned)(wf[q]*16777216.0f + 0.5f);
            if (wfix > 0xFFFFFFu) wfix = 0xFFFFFFu;
            unsigned p = atomicAdd(&cur[((unsigned)c) >> 8], 1u);
            int2 rv; rv.x = rr[q];
            rv.y = (int)((((unsigned)(c & 255)) << 24) | wfix);
            rec[p] = rv;
        }
    }
}

// ---------- per-bucket weighted degree -> dis, before CSR build ----------
__global__ __launch_bounds__(256) void bucket_deg(
        const int2* __restrict__ rec, const int* __restrict__ gbase,
        float* __restrict__ dis){
    __shared__ unsigned wsum[256];
    int b = blockIdx.x, tid = threadIdx.x;
    wsum[tid] = 0u;
    __syncthreads();
    int k0 = gbase[b], k1 = gbase[b+1];
    for (int i = k0 + tid; i < k1; i += 256){
        int2 r = rec[i];
        atomicAdd(&wsum[((unsigned)r.y) >> 24], ((unsigned)r.y) & 0xFFFFFFu);
    }
    __syncthreads();
    float deg = (float)wsum[tid] * (1.0f/16777216.0f);
    dis[(b<<8) + tid] = rsqrtf(deg + 1.0f);   // + self-loop weight
}

// ---------- pass C: per-bucket exact CSR build, all in LDS ----------
// edge_s.x packs clow<<24 | row; edge_s.y = dis[r]*w*dis[c] fully folded.
__global__ __launch_bounds__(256) void bucket_csr(
        const int2* __restrict__ rec, const int* __restrict__ gbase,
        const float* __restrict__ dis,
        int2* __restrict__ edge_s, int* __restrict__ offsets){
    __shared__ int2 S[BKT_CAP];
    __shared__ unsigned cnt[256];
    __shared__ unsigned cur[256];
    __shared__ float dloc[256];
    int b = blockIdx.x, tid = threadIdx.x;
    int k0 = gbase[b], k1 = gbase[b+1];
    int n = k1 - k0;
    cnt[tid] = 0u;
    dloc[tid] = dis[(b<<8) + tid];
    __syncthreads();
    bool staged = (n <= BKT_CAP);
    for (int i = tid; i < n; i += 256){
        int2 r = rec[k0 + i];
        if (staged) S[i] = r;
        atomicAdd(&cnt[((unsigned)r.y) >> 24], 1u);
    }
    __syncthreads();
    unsigned v = cnt[tid];
    #pragma unroll
    for (int off = 1; off < 256; off <<= 1){
        unsigned t = (tid >= off) ? cnt[tid - off] : 0u;
        __syncthreads();
        cnt[tid] += t;
        __syncthreads();
    }
    unsigned excl = cnt[tid] - v;
    cur[tid] = excl;
    offsets[(b<<8) + tid] = k0 + (int)excl;
    __syncthreads();
    for (int i = tid; i < n; i += 256){
        int2 r = staged ? S[i] : rec[k0 + i];
        unsigned clow = ((unsigned)r.y) >> 24;
        unsigned wfix = ((unsigned)r.y) & 0xFFFFFFu;
        float sv = (float)wfix * (1.0f/16777216.0f) * dloc[clow];
        sv = dis[r.x] * sv;
        unsigned p = atomicAdd(&cur[clow], 1u);
        int2 o; o.x = (int)((clow << 24) | (unsigned)r.x); o.y = __float_as_int(sv);
        edge_s[k0 + (int)p] = o;
    }
}

// ---------- R25: x -> f16 copy (3 MB, fits each XCD's 4 MB L2) ----------
// aggx_k issues 2M random x-row gathers; fp32 rows = 32B/edge (64MB) from a
// 6MB table that does NOT fit a per-XCD L2. f16 rows = 16B/edge (32MB) from
// a 3MB L2-resident table: halves bytes AND miss rate. (R19 tested f16-x on
// the broken edge-parallel kernel; this is the node-parallel application.)
__global__ __launch_bounds__(256) void x2h(
        const float* __restrict__ x, _Float16* __restrict__ xh){
    int i = blockIdx.x*1024 + threadIdx.x*4;
    float4 v = *(const float4*)&x[i];
    half4 h;
    h[0] = (_Float16)v.x; h[1] = (_Float16)v.y;
    h[2] = (_Float16)v.z; h[3] = (_Float16)v.w;
    *(half4*)&xh[i] = h;
}

// ---------- layer-1 aggregation, node-parallel, f16 gather ----------
// R17-R19 lesson: edge-parallel LDS-atomic variants all ~90us; this form ~40us.
__global__ __launch_bounds__(256) void aggx_k(
        const int* __restrict__ offsets, const int2* __restrict__ edge_s,
        const float* __restrict__ dis, const float* __restrict__ x,
        const _Float16* __restrict__ xh, float* __restrict__ ax){
    int g   = blockIdx.x*32 + (threadIdx.x >> 3);
    int sub = threadIdx.x & 7;
    float d = dis[g];
    float acc = x[(size_t)g*8 + sub]*d*d;   // self-loop stays fp32
    int k  = offsets[g];
    int k1 = offsets[g+1];
    for (; k+4 <= k1; k += 4){
        int2 e0 = edge_s[k], e1 = edge_s[k+1], e2 = edge_s[k+2], e3 = edge_s[k+3];
        float v0 = (float)xh[(size_t)(e0.x & 0xFFFFFF)*8 + sub];
        float v1 = (float)xh[(size_t)(e1.x & 0xFFFFFF)*8 + sub];
        float v2 = (float)xh[(size_t)(e2.x & 0xFFFFFF)*8 + sub];
        float v3 = (float)xh[(size_t)(e3.x & 0xFFFFFF)*8 + sub];
        acc += v0*__int_as_float(e0.y);
        acc += v1*__int_as_float(e1.y);
        acc += v2*__int_as_float(e2.y);
        acc += v3*__int_as_float(e3.y);
    }
    for (; k < k1; k++){
        int2 e0 = edge_s[k];
        acc += (float)xh[(size_t)(e0.x & 0xFFFFFF)*8 + sub]*__int_as_float(e0.y);
    }
    ax[(size_t)g*8 + sub] = acc;
}

// ---------- BN1 stats only (gcnA1 intermediate eliminated in R24) ----------
__global__ __launch_bounds__(256) void lin1b_stats(
        const float* __restrict__ ax, const float* __restrict__ W1,
        const float* __restrict__ b1,
        float* __restrict__ gsum, float* __restrict__ gsq){
    __shared__ float Ws[512];
    for (int i = threadIdx.x; i < 512; i += 256) Ws[i] = W1[i];
    __syncthreads();
    int f = threadIdx.x & 63;
    float wc[8];
    #pragma unroll
    for (int q = 0; q < 8; q++) wc[q] = Ws[q*64 + f];
    float bb = b1[f];
    float s = 0.f, s2 = 0.f;
    int stride = gridDim.x*blockDim.x;   // multiple of 64
    for (int idx = blockIdx.x*blockDim.x + threadIdx.x; idx < N_NODES*64; idx += stride){
        int j = idx >> 6;
        const float* ar = ax + (size_t)j*8;
        float acc = bb;
        #pragma unroll
        for (int q = 0; q < 8; q++) acc += ar[q]*wc[q];
        float v = fmaxf(acc, 0.f);
        s += v; s2 += v*v;
    }
    __shared__ float s1m[256], s2m[256];
    s1m[threadIdx.x] = s; s2m[threadIdx.x] = s2;
    __syncthreads();
    if (threadIdx.x < 64){
        float t1 = s1m[threadIdx.x]+s1m[threadIdx.x+64]+s1m[threadIdx.x+128]+s1m[threadIdx.x+192];
        float t2 = s2m[threadIdx.x]+s2m[threadIdx.x+64]+s2m[threadIdx.x+128]+s2m[threadIdx.x+192];
        atomicAdd(&gsum[threadIdx.x], t1);
        atomicAdd(&gsq[threadIdx.x], t2);
    }
}

// ---------- lin2_bn: recompute gcn1 from ax, then h1H + hlinH ----------
// Same fp32 expression/order as lin1b_stats -> bit-identical values.
#define L2ROWS 128
#define XS2    132
__global__ __launch_bounds__(128) void lin2_bn(
        const float* __restrict__ ax, const float* __restrict__ W1,
        const float* __restrict__ b1,
        const float* __restrict__ gsum, const float* __restrict__ gsq,
        const float* __restrict__ g1, const float* __restrict__ be1,
        const float* __restrict__ W2,
        _Float16* __restrict__ h1H, float* __restrict__ hlinH){
    __shared__ float Ws[64*64];
    __shared__ float W1s[512];
    __shared__ float b1s[64];
    __shared__ float xsT[64*XS2];
    int tid = threadIdx.x;
    int r0 = blockIdx.x * L2ROWS;

    for (int i = tid; i < 1024; i += 128)
        *(float4*)&Ws[i*4] = *(const float4*)&W2[i*4];
    for (int i = tid; i < 512; i += 128) W1s[i] = W1[i];
    if (tid < 64) b1s[tid] = b1[tid];

    int k4 = tid & 15;
    int rb = tid >> 4;
    float scv[4], shv[4];
    #pragma unroll
    for (int q = 0; q < 4; q++){
        int f = k4*4 + q;
        float mean = gsum[f]*(1.0f/(float)N_NODES);
        float var  = fmaxf(gsq[f]*(1.0f/(float)N_NODES) - mean*mean, 0.f);
        float sc_  = g1[f]*rsqrtf(var + BN_EPS);
        scv[q] = sc_; shv[q] = be1[f] - mean*sc_;
    }
    __syncthreads();   // W1s/b1s ready

    for (int it = 0; it < 16; it++){
        int r = it*8 + rb;
        const float* arp = &ax[(size_t)(r0+r)*8];
        float4 a0 = *(const float4*)arp;
        float4 a1 = *(const float4*)(arp+4);
        float av[8] = {a0.x,a0.y,a0.z,a0.w,a1.x,a1.y,a1.z,a1.w};
        float4 v;
        #pragma unroll
        for (int q = 0; q < 4; q++){
            int f = k4*4 + q;
            float acc = b1s[f];
            #pragma unroll
            for (int p = 0; p < 8; p++) acc += av[p]*W1s[p*64 + f];
            float relu = fmaxf(acc, 0.f);
            v[q] = relu*scv[q] + shv[q];
        }
        half4 hh;
        hh[0]=(_Float16)v[0]; hh[1]=(_Float16)v[1]; hh[2]=(_Float16)v[2]; hh[3]=(_Float16)v[3];
        *(half4*)&h1H[(size_t)(r0+r)*64 + k4*4] = hh;
        xsT[(k4*4+0)*XS2 + r] = v[0];
        xsT[(k4*4+1)*XS2 + r] = v[1];
        xsT[(k4*4+2)*XS2 + r] = v[2];
        xsT[(k4*4+3)*XS2 + r] = v[3];
    }
    __syncthreads();

    int cg = tid & 7;
    int rg = tid >> 3;
    float acc[8][8];
    #pragma unroll
    for (int i = 0; i < 8; i++)
        #pragma unroll
        for (int j = 0; j < 8; j++) acc[i][j] = 0.f;

    float4 a0 = *(float4*)&xsT[0*XS2 + rg*8];
    float4 a1 = *(float4*)&xsT[0*XS2 + rg*8 + 4];
    float4 w0 = *(float4*)&Ws[0*64 + cg*8];
    float4 w1 = *(float4*)&Ws[0*64 + cg*8 + 4];
    for (int k = 0; k < 64; k++){
        float4 na0, na1, nw0, nw1;
        if (k < 63){
            na0 = *(float4*)&xsT[(k+1)*XS2 + rg*8];
            na1 = *(float4*)&xsT[(k+1)*XS2 + rg*8 + 4];
            nw0 = *(float4*)&Ws[(k+1)*64 + cg*8];
            nw1 = *(float4*)&Ws[(k+1)*64 + cg*8 + 4];
        }
        float ar[8] = {a0.x,a0.y,a0.z,a0.w,a1.x,a1.y,a1.z,a1.w};
        float wcv[8] = {w0.x,w0.y,w0.z,w0.w,w1.x,w1.y,w1.z,w1.w};
        #pragma unroll
        for (int i = 0; i < 8; i++)
            #pragma unroll
            for (int j = 0; j < 8; j++) acc[i][j] += ar[i]*wcv[j];
        a0=na0; a1=na1; w0=nw0; w1=nw1;
    }
    #pragma unroll
    for (int i = 0; i < 8; i++){
        size_t r = (size_t)(r0 + rg*8 + i);
        float4 pk;
        pk.x = packf16(acc[i][0], acc[i][1]);
        pk.y = packf16(acc[i][2], acc[i][3]);
        pk.z = packf16(acc[i][4], acc[i][5]);
        pk.w = packf16(acc[i][6], acc[i][7]);
        *(float4*)&hlinH[r*32 + cg*4] = pk;
    }
}

// ---------- layer-2 gather over packed f16 rows, one-shot grid (max MLP) ----------
__global__ __launch_bounds__(256) void gather2h(
        const int* __restrict__ offsets, const int2* __restrict__ edge_s,
        const float* __restrict__ dis, const float* __restrict__ hlinH,
        const float* __restrict__ bias, float* __restrict__ g2Hf){
    int j = blockIdx.x*8 + (threadIdx.x >> 5);
    int p = threadIdx.x & 31;
    float d = dis[j];
    float dd = d*d;
    F16x2U u; u.f = hlinH[(size_t)j*32 + p];
    float ax = (float)u.h[0]*dd;
    float ay = (float)u.h[1]*dd;
    int k  = offsets[j];
    int k1 = offsets[j+1];
    for (; k+4 <= k1; k += 4){
        int2 e0 = edge_s[k], e1 = edge_s[k+1], e2 = edge_s[k+2], e3 = edge_s[k+3];
        F16x2U a, b, c, e;
        a.f = hlinH[(size_t)(e0.x & 0xFFFFFF)*32 + p];
        b.f = hlinH[(size_t)(e1.x & 0xFFFFFF)*32 + p];
        c.f = hlinH[(size_t)(e2.x & 0xFFFFFF)*32 + p];
        e.f = hlinH[(size_t)(e3.x & 0xFFFFFF)*32 + p];
        float n0 = __int_as_float(e0.y), n1 = __int_as_float(e1.y);
        float n2 = __int_as_float(e2.y), n3 = __int_as_float(e3.y);
        ax += (float)a.h[0]*n0; ay += (float)a.h[1]*n0;
        ax += (float)b.h[0]*n1; ay += (float)b.h[1]*n1;
        ax += (float)c.h[0]*n2; ay += (float)c.h[1]*n2;
        ax += (float)e.h[0]*n3; ay += (float)e.h[1]*n3;
    }
    for (; k < k1; k++){
        int2 e0 = edge_s[k];
        F16x2U a; a.f = hlinH[(size_t)(e0.x & 0xFFFFFF)*32 + p];
        float n0 = __int_as_float(e0.y);
        ax += (float)a.h[0]*n0; ay += (float)a.h[1]*n0;
    }
    float2 bv = *(const float2*)&bias[2*p];
    float vx = fmaxf(ax + bv.x, 0.f);
    float vy = fmaxf(ay + bv.y, 0.f);
    F16x2U o; o.h[0] = (_Float16)vx; o.h[1] = (_Float16)vy;
    g2Hf[(size_t)j*32 + p] = o.f;
}

// ---------- BN2 stats over f16 output (12.3 MB pass) ----------
__global__ __launch_bounds__(256) void stats2h(
        const float* __restrict__ g2Hf, float* __restrict__ gsum2, float* __restrict__ gsq2){
    int p = threadIdx.x & 31;
    float s0 = 0.f, s1 = 0.f, q0 = 0.f, q1 = 0.f;
    int stride = gridDim.x*blockDim.x;   // multiple of 32 -> p constant
    for (int idx = blockIdx.x*blockDim.x + threadIdx.x; idx < N_NODES*32; idx += stride){
        F16x2U u; u.f = g2Hf[idx];
        float vx = (float)u.h[0], vy = (float)u.h[1];
        s0 += vx; q0 += vx*vx;
        s1 += vy; q1 += vy*vy;
    }
    __shared__ float sb[128];
    if (threadIdx.x < 128) sb[threadIdx.x] = 0.f;
    __syncthreads();
    atomicAdd(&sb[2*p],      s0);
    atomicAdd(&sb[2*p+1],    s1);
    atomicAdd(&sb[64+2*p],   q0);
    atomicAdd(&sb[64+2*p+1], q1);
    __syncthreads();
    if (threadIdx.x < 64){
        atomicAdd(&gsum2[threadIdx.x], sb[threadIdx.x]);
        atomicAdd(&gsq2[threadIdx.x],  sb[64+threadIdx.x]);
    }
}

// ---------- LSTM weight prep: B-fragment layout [K/32][256][32] f16 ----------
__global__ void prep_weights(const float* __restrict__ Wih1, const float* __restrict__ Whh1,
                             const float* __restrict__ bih1, const float* __restrict__ bhh1,
                             const float* __restrict__ Wih2, const float* __restrict__ Whh2,
                             const float* __restrict__ bih2, const float* __restrict__ bhh2,
                             _Float16* W1F, _Float16* W2F, float* b1c, float* b2c){
    int idx = blockIdx.x*blockDim.x + threadIdx.x;
    if (idx < 6*256*32){
        int kt = idx >> 13;
        int rem = idx & 8191;
        int n = rem >> 5, kin = rem & 31;
        int k = kt*32 + kin;
        float v = (k < 128) ? Wih1[n*128 + k] : Whh1[n*64 + (k-128)];
        W1F[idx] = (_Float16)v;
    }
    int i2 = idx - 6*256*32;
    if (i2 >= 0 && i2 < 4*256*32){
        int kt = i2 >> 13;
        int rem = i2 & 8191;
        int n = rem >> 5, kin = rem & 31;
        int k = kt*32 + kin;
        float v = (k < 64) ? Wih2[n*64 + k] : Whh2[n*64 + (k-64)];
        W2F[i2] = (_Float16)v;
    }
    int i3 = idx - (6*256*32 + 4*256*32);
    if (i3 >= 0 && i3 < 256) b1c[i3] = bih1[i3] + bhh1[i3];
    int i4 = i3 - 256;
    if (i4 >= 0 && i4 < 256) b2c[i4] = bih2[i4] + bhh2[i4];
}

// ---------- fused 12-step LSTM1+LSTM2, MFMA 16x16x32 f16, 32 rows/block ----------
// R21 known-good form VERBATIM (77.5us at R21-session clock, VGPR 196,
// 2 __syncthreads/step). R22 (gate-split, weights-in-reg) null; R23 (raw
// LDS barrier + sched_barrier) regressed. Structural floor -- do not touch.
#define X1S 200   // halves/row, 400 B
#define X2S 136   // halves/row, 272 B
__global__ __launch_bounds__(256) void lstm_fused(
        const _Float16* __restrict__ h1H, const _Float16* __restrict__ g2H,
        const float* __restrict__ gsum2, const float* __restrict__ gsq2,
        const float* __restrict__ g2bn, const float* __restrict__ be2,
        const _Float16* __restrict__ W1F, const _Float16* __restrict__ W2F,
        const float* __restrict__ b1c, const float* __restrict__ b2c,
        float* __restrict__ h1s, float* __restrict__ h2s){
    __shared__ _Float16 X1h[32*X1S];
    __shared__ _Float16 X2h[32*X2S];
    int tid = threadIdx.x;
    int j0 = blockIdx.x*32;
    int w    = tid >> 6;
    int lane = tid & 63;
    int quad = lane >> 4;
    int l16  = lane & 15;
    int u    = 16*w + l16;

    int c4 = tid & 15;
    int sr = (tid >> 4) & 15;          // this thread stages rows sr and sr+16
    int sjA = j0 + sr;
    int sjB = sjA + 16;
    int sbA = sjA / NN_SZ, snA = sjA - sbA*NN_SZ;
    int sbB = sjB / NN_SZ, snB = sjB - sbB*NN_SZ;   // block may straddle batch
    size_t rbaseA = ((size_t)(sbA*T_WIN)*NN_SZ + snA)*64 + c4*4;
    size_t rbaseB = ((size_t)(sbB*T_WIN)*NN_SZ + snB)*64 + c4*4;
    const size_t tstep = (size_t)NN_SZ*64;
    float sc2v[4], sh2v[4];
    #pragma unroll
    for (int q = 0; q < 4; q++){
        int f = c4*4 + q;
        float mean = gsum2[f]*(1.0f/(float)N_NODES);
        float var  = fmaxf(gsq2[f]*(1.0f/(float)N_NODES) - mean*mean, 0.f);
        float sc_  = g2bn[f]*rsqrtf(var + BN_EPS);
        sc2v[q] = sc_; sh2v[q] = be2[f] - mean*sc_;
    }

    float c1r[2][4], c2r[2][4], h2r[2][4];
    #pragma unroll
    for (int tle = 0; tle < 2; tle++)
        #pragma unroll
        for (int i = 0; i < 4; i++){ c1r[tle][i] = 0.f; c2r[tle][i] = 0.f; h2r[tle][i] = 0.f; }

    float bi1 = b1c[u], bf1 = b1c[64+u], bg1 = b1c[128+u], bo1 = b1c[192+u];
    float bi2 = b2c[u], bf2 = b2c[64+u], bg2 = b2c[128+u], bo2 = b2c[192+u];

    {
        half4 v0A = *(const half4*)&h1H[rbaseA];
        half4 g4A = *(const half4*)&g2H[rbaseA];
        half4 v0B = *(const half4*)&h1H[rbaseB];
        half4 g4B = *(const half4*)&g2H[rbaseB];
        half4 v1A, v1B;
        #pragma unroll
        for (int q = 0; q < 4; q++){
            v1A[q] = (_Float16)((float)g4A[q]*sc2v[q] + sh2v[q]);
            v1B[q] = (_Float16)((float)g4B[q]*sc2v[q] + sh2v[q]);
        }
        *(half4*)&X1h[sr*X1S + c4*4]             = v0A;
        *(half4*)&X1h[sr*X1S + 64 + c4*4]        = v1A;
        *(half4*)&X1h[sr*X1S + 128 + c4*4]       = (half4){0,0,0,0};
        *(half4*)&X1h[(sr+16)*X1S + c4*4]        = v0B;
        *(half4*)&X1h[(sr+16)*X1S + 64 + c4*4]   = v1B;
        *(half4*)&X1h[(sr+16)*X1S + 128 + c4*4]  = (half4){0,0,0,0};
    }
    __syncthreads();

    for (int t = 0; t < T_WIN; t++){
        half4 nv0A, ng4A, nv0B, ng4B;
        if (t < T_WIN-1){
            size_t rbA = rbaseA + (size_t)(t+1)*tstep;
            size_t rbB = rbaseB + (size_t)(t+1)*tstep;
            nv0A = *(const half4*)&h1H[rbA];
            ng4A = *(const half4*)&g2H[rbA];
            nv0B = *(const half4*)&h1H[rbB];
            ng4B = *(const half4*)&g2H[rbB];
        }

        // ---- phase 1: gates1 = X1 @ W1^T, K=192, 2 row-tiles per B-frag ----
        f32x4 acc[2][4];
        #pragma unroll
        for (int tle = 0; tle < 2; tle++)
            #pragma unroll
            for (int g = 0; g < 4; g++) acc[tle][g] = (f32x4){0.f,0.f,0.f,0.f};
        #pragma unroll
        for (int kt = 0; kt < 6; kt++){
            half8 a0 = *(const half8*)&X1h[l16*X1S + kt*32 + quad*8];
            half8 a1 = *(const half8*)&X1h[(l16+16)*X1S + kt*32 + quad*8];
            #pragma unroll
            for (int g = 0; g < 4; g++){
                half8 b = *(const half8*)&W1F[(size_t)(kt*256 + 64*g + u)*32 + quad*8];
                acc[0][g] = __builtin_amdgcn_mfma_f32_16x16x32_f16(a0, b, acc[0][g], 0, 0, 0);
                acc[1][g] = __builtin_amdgcn_mfma_f32_16x16x32_f16(a1, b, acc[1][g], 0, 0, 0);
            }
        }
        __syncthreads();

        // ---- cell update 1 (both tiles) + stage X2 + commit t+1 X1 ----
        #pragma unroll
        for (int tle = 0; tle < 2; tle++){
            #pragma unroll
            for (int r = 0; r < 4; r++){
                int rowl = quad*4 + r + 16*tle;
                float gi = acc[tle][0][r] + bi1;
                float gf = acc[tle][1][r] + bf1;
                float gg = acc[tle][2][r] + bg1;
                float go = acc[tle][3][r] + bo1;
                float cn = fsig(gf)*c1r[tle][r] + fsig(gi)*ftanh(gg);
                float hn = fsig(go)*ftanh(cn);
                c1r[tle][r] = cn;
                X2h[rowl*X2S + u]      = (_Float16)hn;
                X2h[rowl*X2S + 64 + u] = (_Float16)h2r[tle][r];
                X1h[rowl*X1S + 128 + u] = (_Float16)hn;
                if (t == T_WIN-1) h1s[(size_t)(j0 + rowl)*64 + u] = hn;
            }
        }
        if (t < T_WIN-1){
            half4 v1A, v1B;
            #pragma unroll
            for (int q = 0; q < 4; q++){
                v1A[q] = (_Float16)((float)ng4A[q]*sc2v[q] + sh2v[q]);
                v1B[q] = (_Float16)((float)ng4B[q]*sc2v[q] + sh2v[q]);
            }
            *(half4*)&X1h[sr*X1S + c4*4]            = nv0A;
            *(half4*)&X1h[sr*X1S + 64 + c4*4]       = v1A;
            *(half4*)&X1h[(sr+16)*X1S + c4*4]       = nv0B;
            *(half4*)&X1h[(sr+16)*X1S + 64 + c4*4]  = v1B;
        }
        __syncthreads();

        // ---- phase 2: gates2 = X2 @ W2^T, K=128 ----
        f32x4 acc2[2][4];
        #pragma unroll
        for (int tle = 0; tle < 2; tle++)
            #pragma unroll
            for (int g = 0; g < 4; g++) acc2[tle][g] = (f32x4){0.f,0.f,0.f,0.f};
        #pragma unroll
        for (int kt = 0; kt < 4; kt++){
            half8 a0 = *(const half8*)&X2h[l16*X2S + kt*32 + quad*8];
            half8 a1 = *(const half8*)&X2h[(l16+16)*X2S + kt*32 + quad*8];
            #pragma unroll
            for (int g = 0; g < 4; g++){
                half8 b = *(const half8*)&W2F[(size_t)(kt*256 + 64*g + u)*32 + quad*8];
                acc2[0][g] = __builtin_amdgcn_mfma_f32_16x16x32_f16(a0, b, acc2[0][g], 0, 0, 0);
                acc2[1][g] = __builtin_amdgcn_mfma_f32_16x16x32_f16(a1, b, acc2[1][g], 0, 0, 0);
            }
        }

        // ---- cell update 2 (both tiles) ----
        #pragma unroll
        for (int tle = 0; tle < 2; tle++){
            #pragma unroll
            for (int r = 0; r < 4; r++){
                int rowl = quad*4 + r + 16*tle;
                float gi = acc2[tle][0][r] + bi2;
                float gf = acc2[tle][1][r] + bf2;
                float gg = acc2[tle][2][r] + bg2;
                float go = acc2[tle][3][r] + bo2;
                float cn = fsig(gf)*c2r[tle][r] + fsig(gi)*ftanh(gg);
                float hn = fsig(go)*ftanh(cn);
                c2r[tle][r] = cn;
                h2r[tle][r] = hn;
                if (t == T_WIN-1) h2s[(size_t)(j0 + rowl)*64 + u] = hn;
            }
        }
    }
}

// ---------- FC head ----------
__global__ __launch_bounds__(256) void fc_head(
        const float* __restrict__ h1s, const float* __restrict__ h2s,
        const float* __restrict__ inner, const float* __restrict__ x,
        const float* __restrict__ fc1_w, const float* __restrict__ fc1_b,
        const float* __restrict__ fc3_w, const float* __restrict__ fc3_b,
        float* __restrict__ out){
    __shared__ float zsm[4][226];
    int wv = threadIdx.x >> 6;
    int f  = threadIdx.x & 63;
    int j  = blockIdx.x*4 + wv;
    int b = j / NN_SZ, n = j - b*NN_SZ;
    for (int k = f; k < 225; k += 64){
        float v;
        if (k < 64)        v = h1s[j*64 + k];
        else if (k < 128)  v = h2s[j*64 + (k-64)];
        else if (k == 128) v = inner[j];
        else {
            int kk = k - 129;
            int w_ = kk >> 3, ff = kk & 7;
            v = x[((b*T_WIN + w_)*NN_SZ + n)*FIN + ff];
        }
        zsm[wv][k] = v;
    }
    __syncthreads();
    float acc = fc1_b[f];
    for (int k = 0; k < 225; k++) acc += zsm[wv][k]*fc1_w[k*64 + f];
    float p = fmaxf(acc, 0.f) * fc3_w[f];
    #pragma unroll
    for (int off = 32; off > 0; off >>= 1) p += __shfl_down(p, off, 64);
    if (f == 0) out[j] = fmaxf(p + fc3_b[0], 0.f);
}

extern "C" void kernel_launch(void* const* d_in, const int* in_sizes, int n_in,
                              void* d_out, int out_size, void* d_ws, size_t ws_size,
                              hipStream_t stream){
    const int*   adj  = (const int*)d_in[0];
    const int*   row  = adj;
    const int*   col  = adj + EDGES;
    const float* aw   = (const float*)d_in[1];
    const float* x    = (const float*)d_in[2];
    const float* inner= (const float*)d_in[3];
    const float* W1   = (const float*)d_in[4];
    const float* b1   = (const float*)d_in[5];
    const float* W2   = (const float*)d_in[6];
    const float* b2   = (const float*)d_in[7];
    const float* g1   = (const float*)d_in[8];
    const float* be1  = (const float*)d_in[9];
    const float* g2   = (const float*)d_in[10];
    const float* be2  = (const float*)d_in[11];
    const float* Wih1 = (const float*)d_in[12];
    const float* Whh1 = (const float*)d_in[13];
    const float* bih1 = (const float*)d_in[14];
    const float* bhh1 = (const float*)d_in[15];
    const float* Wih2 = (const float*)d_in[16];
    const float* Whh2 = (const float*)d_in[17];
    const float* bih2 = (const float*)d_in[18];
    const float* bhh2 = (const float*)d_in[19];
    const float* fc1w = (const float*)d_in[20];
    const float* fc1b = (const float*)d_in[21];
    const float* fc3w = (const float*)d_in[22];
    const float* fc3b = (const float*)d_in[23];
    float* out = (float*)d_out;

    float* ws = (float*)d_ws;
    const size_t NB = (size_t)N_NODES*64;            // 12,288,000 floats
    float* bufX = ws;                                 // blockbase -> hlinH -> LSTM outs + W
    float* bufY = ws + NB;                            // rec -> g2H (f16)
    float* bufZ = ws + 2*NB;                          // h1H (f16) + ax
    int2*  edge_s  = (int2*)(ws + 3*NB);              // E int2
    float* degdis  = ws + 3*NB + (size_t)2*EDGES;     // N (dis)
    float* gsum    = degdis + N_NODES;                // 64
    float* gsq     = gsum + 64;                       // 64
    float* gsum2   = gsq + 64;                        // 64
    float* gsq2    = gsum2 + 64;                      // 64
    unsigned* gcount = (unsigned*)(gsq2 + 64);        // NBKT
    int* gbase   = (int*)(gcount + NBKT);             // NBKT+1
    int* offsets = gbase + (NBKT + 2);                // N+1
    _Float16* xh = (_Float16*)(offsets + (N_NODES + 2));  // N*8 f16 (3 MB)

    // preprocessing aliases (dead before their buffers' later users)
    int* blockbase = (int*)bufX;                      // NBLKA*NBKT ints (768 KB)
    int2* rec      = (int2*)bufY;                     // E int2 (16 MB)

    // phase-1 aliases
    float* hlinH = bufX;                              // N*32 floats (f16 pairs)
    _Float16* h1H = (_Float16*)bufZ;                  // N*64 f16
    float* ax    = bufZ + (size_t)N_NODES*32 + 64;    // N*8 fp32
    float* g2Hf  = bufY;                              // N*32 floats (f16 pairs)

    // LSTM-phase aliases into bufX (hlinH dead after gather2h)
    float* h1s = bufX;
    float* h2s = bufX + (size_t)BN_ROWS*64;
    _Float16* W1F = (_Float16*)(bufX + (size_t)4*BN_ROWS*64);
    _Float16* W2F = W1F + 6*256*32;
    float* b1c = (float*)(W2F + 4*256*32);
    float* b2c = b1c + 256;

    // ---- edge preprocessing: LDS-privatized two-level counting sort ----
    hipMemsetAsync(gcount, 0, NBKT*sizeof(unsigned), stream);
    hipMemsetAsync(gsum, 0, 256*sizeof(float), stream);   // gsum/gsq/gsum2/gsq2
    hist_coarse   <<<NBLKA, 256, 0, stream>>>(col, gcount, blockbase);
    scan_bkt      <<<1, 1024, 0, stream>>>(gcount, gbase, offsets);
    scatter_bucket<<<NBLKA, 256, 0, stream>>>(row, col, aw, blockbase, gbase, rec);
    bucket_deg    <<<NBKT, 256, 0, stream>>>(rec, gbase, degdis);
    bucket_csr    <<<NBKT, 256, 0, stream>>>(rec, gbase, degdis, edge_s, offsets);

    // ---- GCN layer 1 (node-parallel, f16 L2-resident gather table) ----
    x2h<<<N_NODES*8/1024, 256, 0, stream>>>(x, xh);
    aggx_k<<<N_NODES/32, 256, 0, stream>>>(offsets, edge_s, degdis, x, xh, ax);
    lin1b_stats<<<1024, 256, 0, stream>>>(ax, W1, b1, gsum, gsq);

    // ---- BN1 + layer-2 linear, gcn1 recomputed from ax (no 49MB intermediate) ----
    lin2_bn<<<N_NODES/L2ROWS, 128, 0, stream>>>(ax, W1, b1, gsum, gsq, g1, be1, W2, h1H, hlinH);

    // ---- GCN layer 2 (one-shot grid for max MLP) + separate f16 stats pass ----
    gather2h<<<N_NODES/8, 256, 0, stream>>>(offsets, edge_s, degdis, hlinH, b2, g2Hf);
    stats2h<<<1024, 256, 0, stream>>>(g2Hf, gsum2, gsq2);

    // ---- fused 12-step LSTM (32 rows/block, R21 known-good) ----
    prep_weights<<<(6*256*32 + 4*256*32 + 512 + 255)/256, 256, 0, stream>>>(
        Wih1, Whh1, bih1, bhh1, Wih2, Whh2, bih2, bhh2, W1F, W2F, b1c, b2c);
    lstm_fused<<<BN_ROWS/32, 256, 0, stream>>>(h1H, (const _Float16*)g2Hf,
                                               gsum2, gsq2, g2, be2,
                                               W1F, W2F, b1c, b2c, h1s, h2s);

    // ---- FC head ----
    fc_head<<<BN_ROWS/4, 256, 0, stream>>>(h1s, h2s, inner, x, fc1w, fc1b, fc3w, fc3b, out);
}

// Round 14
// 474.739 us; speedup vs baseline: 1.0969x; 1.0254x over previous
//
#include <hip/hip_runtime.h>
#include <math.h>

#define N_NODES 192000
#define EDGES   2000000
#define HID     64
#define BN_ROWS 16000   // B*NN
#define T_WIN   12
#define B_SZ    8
#define NN_SZ   2000
#define FIN     8
#define BN_EPS  1e-5f

// two-level bucket sort params: bucket = col >> 8 (256 nodes/bucket)
#define NBKT    750
#define NBLKA   256
#define ACHUNK  7824     // 256*7824 = 2,002,944 >= EDGES, divisible by 4
#define BKT_CAP 5120     // mean bucket = 2667, +47 sigma headroom

typedef _Float16 f16x2 __attribute__((ext_vector_type(2)));
typedef _Float16 half4 __attribute__((ext_vector_type(4)));
typedef _Float16 half8 __attribute__((ext_vector_type(8)));
typedef float    f32x4 __attribute__((ext_vector_type(4)));
union F16x2U { float f; f16x2 h; };

// fast sigmoid/tanh: v_exp_f32 + v_rcp_f32 (~1 ulp; f16 inputs dominate error)
__device__ __forceinline__ float frcp(float x){
#if __has_builtin(__builtin_amdgcn_rcpf)
    return __builtin_amdgcn_rcpf(x);
#else
    return 1.0f/x;
#endif
}
__device__ __forceinline__ float fsig(float x){ return frcp(1.0f + __expf(-x)); }
__device__ __forceinline__ float ftanh(float x){ return fmaf(2.0f, fsig(2.0f*x), -1.0f); }

__device__ __forceinline__ float packf16(float a, float b){
    F16x2U u; u.h[0] = (_Float16)a; u.h[1] = (_Float16)b; return u.f;
}

// ---------- pass A: per-block LDS histogram over coarse buckets ----------
__global__ __launch_bounds__(256) void hist_coarse(
        const int* __restrict__ col, unsigned* __restrict__ gcount,
        int* __restrict__ blockbase){
    __shared__ unsigned bh[NBKT];
    int bl = blockIdx.x, tid = threadIdx.x;
    for (int i = tid; i < NBKT; i += 256) bh[i] = 0u;
    __syncthreads();
    int e0 = bl*ACHUNK;
    int e1 = e0 + ACHUNK; if (e1 > EDGES) e1 = EDGES;
    for (int e = e0 + tid*4; e < e1; e += 1024){
        int4 c4 = *(const int4*)&col[e];
        atomicAdd(&bh[((unsigned)c4.x) >> 8], 1u);
        atomicAdd(&bh[((unsigned)c4.y) >> 8], 1u);
        atomicAdd(&bh[((unsigned)c4.z) >> 8], 1u);
        atomicAdd(&bh[((unsigned)c4.w) >> 8], 1u);
    }
    __syncthreads();
    for (int i = tid; i < NBKT; i += 256)
        blockbase[bl*NBKT + i] = (int)atomicAdd(&gcount[i], bh[i]);
}

// ---------- scan of 750 bucket totals ----------
__global__ __launch_bounds__(1024) void scan_bkt(
        const unsigned* __restrict__ gcount, int* __restrict__ gbase,
        int* __restrict__ offsets){
    __shared__ int sm[1024];
    int tid = threadIdx.x;
    int v = (tid < NBKT) ? (int)gcount[tid] : 0;
    sm[tid] = v;
    __syncthreads();
    #pragma unroll
    for (int off = 1; off < 1024; off <<= 1){
        int t = (tid >= off) ? sm[tid - off] : 0;
        __syncthreads();
        sm[tid] += t;
        __syncthreads();
    }
    if (tid < NBKT) gbase[tid] = sm[tid] - v;
    if (tid == NBKT) gbase[NBKT] = EDGES;
    if (tid == NBKT+1) offsets[N_NODES] = EDGES;
}

// ---------- pass B: scatter edges into bucket regions (LDS cursors) ----------
__global__ __launch_bounds__(256) void scatter_bucket(
        const int* __restrict__ row, const int* __restrict__ col,
        const float* __restrict__ w, const int* __restrict__ blockbase,
        const int* __restrict__ gbase, int2* __restrict__ rec){
    __shared__ unsigned cur[NBKT];
    int bl = blockIdx.x, tid = threadIdx.x;
    for (int i = tid; i < NBKT; i += 256)
        cur[i] = (unsigned)(gbase[i] + blockbase[bl*NBKT + i]);
    __syncthreads();
    int e0 = bl*ACHUNK;
    int e1 = e0 + ACHUNK; if (e1 > EDGES) e1 = EDGES;
    for (int e = e0 + tid*4; e < e1; e += 1024){
        int4 r4 = *(const int4*)&row[e];
        int4 c4 = *(const int4*)&col[e];
        float4 w4 = *(const float4*)&w[e];
        int cc[4] = {c4.x, c4.y, c4.z, c4.w};
        int rr[4] = {r4.x, r4.y, r4.z, r4.w};
        float wf[4] = {w4.x, w4.y, w4.z, w4.w};
        #pragma unroll
        for (int q = 0; q < 4; q++){
            int c = cc[q];
            unsigned wfix = (unsigned)(wf[q]*16777216.0f + 0.5f);
            if (wfix > 0xFFFFFFu) wfix = 0xFFFFFFu;
            unsigned p = atomicAdd(&cur[((unsigned)c) >> 8], 1u);
            int2 rv; rv.x = rr[q];
            rv.y = (int)((((unsigned)(c & 255)) << 24) | wfix);
            rec[p] = rv;
        }
    }
}

// ---------- per-bucket weighted degree -> dis, before CSR build ----------
__global__ __launch_bounds__(256) void bucket_deg(
        const int2* __restrict__ rec, const int* __restrict__ gbase,
        float* __restrict__ dis){
    __shared__ unsigned wsum[256];
    int b = blockIdx.x, tid = threadIdx.x;
    wsum[tid] = 0u;
    __syncthreads();
    int k0 = gbase[b], k1 = gbase[b+1];
    for (int i = k0 + tid; i < k1; i += 256){
        int2 r = rec[i];
        atomicAdd(&wsum[((unsigned)r.y) >> 24], ((unsigned)r.y) & 0xFFFFFFu);
    }
    __syncthreads();
    float deg = (float)wsum[tid] * (1.0f/16777216.0f);
    dis[(b<<8) + tid] = rsqrtf(deg + 1.0f);   // + self-loop weight
}

// ---------- pass C: per-bucket exact CSR build, all in LDS ----------
// edge_s.x packs clow<<24 | row; edge_s.y = dis[r]*w*dis[c] fully folded.
__global__ __launch_bounds__(256) void bucket_csr(
        const int2* __restrict__ rec, const int* __restrict__ gbase,
        const float* __restrict__ dis,
        int2* __restrict__ edge_s, int* __restrict__ offsets){
    __shared__ int2 S[BKT_CAP];
    __shared__ unsigned cnt[256];
    __shared__ unsigned cur[256];
    __shared__ float dloc[256];
    int b = blockIdx.x, tid = threadIdx.x;
    int k0 = gbase[b], k1 = gbase[b+1];
    int n = k1 - k0;
    cnt[tid] = 0u;
    dloc[tid] = dis[(b<<8) + tid];
    __syncthreads();
    bool staged = (n <= BKT_CAP);
    for (int i = tid; i < n; i += 256){
        int2 r = rec[k0 + i];
        if (staged) S[i] = r;
        atomicAdd(&cnt[((unsigned)r.y) >> 24], 1u);
    }
    __syncthreads();
    unsigned v = cnt[tid];
    #pragma unroll
    for (int off = 1; off < 256; off <<= 1){
        unsigned t = (tid >= off) ? cnt[tid - off] : 0u;
        __syncthreads();
        cnt[tid] += t;
        __syncthreads();
    }
    unsigned excl = cnt[tid] - v;
    cur[tid] = excl;
    offsets[(b<<8) + tid] = k0 + (int)excl;
    __syncthreads();
    for (int i = tid; i < n; i += 256){
        int2 r = staged ? S[i] : rec[k0 + i];
        unsigned clow = ((unsigned)r.y) >> 24;
        unsigned wfix = ((unsigned)r.y) & 0xFFFFFFu;
        float sv = (float)wfix * (1.0f/16777216.0f) * dloc[clow];
        sv = dis[r.x] * sv;
        unsigned p = atomicAdd(&cur[clow], 1u);
        int2 o; o.x = (int)((clow << 24) | (unsigned)r.x); o.y = __float_as_int(sv);
        edge_s[k0 + (int)p] = o;
    }
}

// ---------- x -> f16 copy (3 MB, fits each XCD's 4 MB L2) ----------
__global__ __launch_bounds__(256) void x2h(
        const float* __restrict__ x, _Float16* __restrict__ xh){
    int i = blockIdx.x*1024 + threadIdx.x*4;
    float4 v = *(const float4*)&x[i];
    half4 h;
    h[0] = (_Float16)v.x; h[1] = (_Float16)v.y;
    h[2] = (_Float16)v.z; h[3] = (_Float16)v.w;
    *(half4*)&xh[i] = h;
}

// ---------- layer-1 aggregation, node-parallel, f16 gather, ILP x8 ----------
// R26: 4->8 unroll. R25 byte-cut was flat -> testing the last hypothesis:
// ILP starvation (only 4 row-reads in flight vs ~500-900cyc latency, mean
// degree 10.4 -> 2.6 trips). Accumulation order unchanged -> bit-identical.
__global__ __launch_bounds__(256) void aggx_k(
        const int* __restrict__ offsets, const int2* __restrict__ edge_s,
        const float* __restrict__ dis, const float* __restrict__ x,
        const _Float16* __restrict__ xh, float* __restrict__ ax){
    int g   = blockIdx.x*32 + (threadIdx.x >> 3);
    int sub = threadIdx.x & 7;
    float d = dis[g];
    float acc = x[(size_t)g*8 + sub]*d*d;   // self-loop stays fp32
    int k  = offsets[g];
    int k1 = offsets[g+1];
    for (; k+8 <= k1; k += 8){
        int2 e0 = edge_s[k],   e1 = edge_s[k+1], e2 = edge_s[k+2], e3 = edge_s[k+3];
        int2 e4 = edge_s[k+4], e5 = edge_s[k+5], e6 = edge_s[k+6], e7 = edge_s[k+7];
        float v0 = (float)xh[(size_t)(e0.x & 0xFFFFFF)*8 + sub];
        float v1 = (float)xh[(size_t)(e1.x & 0xFFFFFF)*8 + sub];
        float v2 = (float)xh[(size_t)(e2.x & 0xFFFFFF)*8 + sub];
        float v3 = (float)xh[(size_t)(e3.x & 0xFFFFFF)*8 + sub];
        float v4 = (float)xh[(size_t)(e4.x & 0xFFFFFF)*8 + sub];
        float v5 = (float)xh[(size_t)(e5.x & 0xFFFFFF)*8 + sub];
        float v6 = (float)xh[(size_t)(e6.x & 0xFFFFFF)*8 + sub];
        float v7 = (float)xh[(size_t)(e7.x & 0xFFFFFF)*8 + sub];
        acc += v0*__int_as_float(e0.y);
        acc += v1*__int_as_float(e1.y);
        acc += v2*__int_as_float(e2.y);
        acc += v3*__int_as_float(e3.y);
        acc += v4*__int_as_float(e4.y);
        acc += v5*__int_as_float(e5.y);
        acc += v6*__int_as_float(e6.y);
        acc += v7*__int_as_float(e7.y);
    }
    for (; k+4 <= k1; k += 4){
        int2 e0 = edge_s[k], e1 = edge_s[k+1], e2 = edge_s[k+2], e3 = edge_s[k+3];
        float v0 = (float)xh[(size_t)(e0.x & 0xFFFFFF)*8 + sub];
        float v1 = (float)xh[(size_t)(e1.x & 0xFFFFFF)*8 + sub];
        float v2 = (float)xh[(size_t)(e2.x & 0xFFFFFF)*8 + sub];
        float v3 = (float)xh[(size_t)(e3.x & 0xFFFFFF)*8 + sub];
        acc += v0*__int_as_float(e0.y);
        acc += v1*__int_as_float(e1.y);
        acc += v2*__int_as_float(e2.y);
        acc += v3*__int_as_float(e3.y);
    }
    for (; k < k1; k++){
        int2 e0 = edge_s[k];
        acc += (float)xh[(size_t)(e0.x & 0xFFFFFF)*8 + sub]*__int_as_float(e0.y);
    }
    ax[(size_t)g*8 + sub] = acc;
}

// ---------- BN1 stats only (gcnA1 intermediate eliminated in R24) ----------
__global__ __launch_bounds__(256) void lin1b_stats(
        const float* __restrict__ ax, const float* __restrict__ W1,
        const float* __restrict__ b1,
        float* __restrict__ gsum, float* __restrict__ gsq){
    __shared__ float Ws[512];
    for (int i = threadIdx.x; i < 512; i += 256) Ws[i] = W1[i];
    __syncthreads();
    int f = threadIdx.x & 63;
    float wc[8];
    #pragma unroll
    for (int q = 0; q < 8; q++) wc[q] = Ws[q*64 + f];
    float bb = b1[f];
    float s = 0.f, s2 = 0.f;
    int stride = gridDim.x*blockDim.x;   // multiple of 64
    for (int idx = blockIdx.x*blockDim.x + threadIdx.x; idx < N_NODES*64; idx += stride){
        int j = idx >> 6;
        const float* ar = ax + (size_t)j*8;
        float acc = bb;
        #pragma unroll
        for (int q = 0; q < 8; q++) acc += ar[q]*wc[q];
        float v = fmaxf(acc, 0.f);
        s += v; s2 += v*v;
    }
    __shared__ float s1m[256], s2m[256];
    s1m[threadIdx.x] = s; s2m[threadIdx.x] = s2;
    __syncthreads();
    if (threadIdx.x < 64){
        float t1 = s1m[threadIdx.x]+s1m[threadIdx.x+64]+s1m[threadIdx.x+128]+s1m[threadIdx.x+192];
        float t2 = s2m[threadIdx.x]+s2m[threadIdx.x+64]+s2m[threadIdx.x+128]+s2m[threadIdx.x+192];
        atomicAdd(&gsum[threadIdx.x], t1);
        atomicAdd(&gsq[threadIdx.x], t2);
    }
}

// ---------- lin2_bn: recompute gcn1 from ax, then h1H + hlinH ----------
// Same fp32 expression/order as lin1b_stats -> bit-identical values.
#define L2ROWS 128
#define XS2    132
__global__ __launch_bounds__(128) void lin2_bn(
        const float* __restrict__ ax, const float* __restrict__ W1,
        const float* __restrict__ b1,
        const float* __restrict__ gsum, const float* __restrict__ gsq,
        const float* __restrict__ g1, const float* __restrict__ be1,
        const float* __restrict__ W2,
        _Float16* __restrict__ h1H, float* __restrict__ hlinH){
    __shared__ float Ws[64*64];
    __shared__ float W1s[512];
    __shared__ float b1s[64];
    __shared__ float xsT[64*XS2];
    int tid = threadIdx.x;
    int r0 = blockIdx.x * L2ROWS;

    for (int i = tid; i < 1024; i += 128)
        *(float4*)&Ws[i*4] = *(const float4*)&W2[i*4];
    for (int i = tid; i < 512; i += 128) W1s[i] = W1[i];
    if (tid < 64) b1s[tid] = b1[tid];

    int k4 = tid & 15;
    int rb = tid >> 4;
    float scv[4], shv[4];
    #pragma unroll
    for (int q = 0; q < 4; q++){
        int f = k4*4 + q;
        float mean = gsum[f]*(1.0f/(float)N_NODES);
        float var  = fmaxf(gsq[f]*(1.0f/(float)N_NODES) - mean*mean, 0.f);
        float sc_  = g1[f]*rsqrtf(var + BN_EPS);
        scv[q] = sc_; shv[q] = be1[f] - mean*sc_;
    }
    __syncthreads();   // W1s/b1s ready

    for (int it = 0; it < 16; it++){
        int r = it*8 + rb;
        const float* arp = &ax[(size_t)(r0+r)*8];
        float4 a0 = *(const float4*)arp;
        float4 a1 = *(const float4*)(arp+4);
        float av[8] = {a0.x,a0.y,a0.z,a0.w,a1.x,a1.y,a1.z,a1.w};
        float4 v;
        #pragma unroll
        for (int q = 0; q < 4; q++){
            int f = k4*4 + q;
            float acc = b1s[f];
            #pragma unroll
            for (int p = 0; p < 8; p++) acc += av[p]*W1s[p*64 + f];
            float relu = fmaxf(acc, 0.f);
            v[q] = relu*scv[q] + shv[q];
        }
        half4 hh;
        hh[0]=(_Float16)v[0]; hh[1]=(_Float16)v[1]; hh[2]=(_Float16)v[2]; hh[3]=(_Float16)v[3];
        *(half4*)&h1H[(size_t)(r0+r)*64 + k4*4] = hh;
        xsT[(k4*4+0)*XS2 + r] = v[0];
        xsT[(k4*4+1)*XS2 + r] = v[1];
        xsT[(k4*4+2)*XS2 + r] = v[2];
        xsT[(k4*4+3)*XS2 + r] = v[3];
    }
    __syncthreads();

    int cg = tid & 7;
    int rg = tid >> 3;
    float acc[8][8];
    #pragma unroll
    for (int i = 0; i < 8; i++)
        #pragma unroll
        for (int j = 0; j < 8; j++) acc[i][j] = 0.f;

    float4 a0 = *(float4*)&xsT[0*XS2 + rg*8];
    float4 a1 = *(float4*)&xsT[0*XS2 + rg*8 + 4];
    float4 w0 = *(float4*)&Ws[0*64 + cg*8];
    float4 w1 = *(float4*)&Ws[0*64 + cg*8 + 4];
    for (int k = 0; k < 64; k++){
        float4 na0, na1, nw0, nw1;
        if (k < 63){
            na0 = *(float4*)&xsT[(k+1)*XS2 + rg*8];
            na1 = *(float4*)&xsT[(k+1)*XS2 + rg*8 + 4];
            nw0 = *(float4*)&Ws[(k+1)*64 + cg*8];
            nw1 = *(float4*)&Ws[(k+1)*64 + cg*8 + 4];
        }
        float ar[8] = {a0.x,a0.y,a0.z,a0.w,a1.x,a1.y,a1.z,a1.w};
        float wcv[8] = {w0.x,w0.y,w0.z,w0.w,w1.x,w1.y,w1.z,w1.w};
        #pragma unroll
        for (int i = 0; i < 8; i++)
            #pragma unroll
            for (int j = 0; j < 8; j++) acc[i][j] += ar[i]*wcv[j];
        a0=na0; a1=na1; w0=nw0; w1=nw1;
    }
    #pragma unroll
    for (int i = 0; i < 8; i++){
        size_t r = (size_t)(r0 + rg*8 + i);
        float4 pk;
        pk.x = packf16(acc[i][0], acc[i][1]);
        pk.y = packf16(acc[i][2], acc[i][3]);
        pk.z = packf16(acc[i][4], acc[i][5]);
        pk.w = packf16(acc[i][6], acc[i][7]);
        *(float4*)&hlinH[r*32 + cg*4] = pk;
    }
}

// ---------- layer-2 gather over packed f16 rows, ILP x8 ----------
__global__ __launch_bounds__(256) void gather2h(
        const int* __restrict__ offsets, const int2* __restrict__ edge_s,
        const float* __restrict__ dis, const float* __restrict__ hlinH,
        const float* __restrict__ bias, float* __restrict__ g2Hf){
    int j = blockIdx.x*8 + (threadIdx.x >> 5);
    int p = threadIdx.x & 31;
    float d = dis[j];
    float dd = d*d;
    F16x2U u; u.f = hlinH[(size_t)j*32 + p];
    float ax = (float)u.h[0]*dd;
    float ay = (float)u.h[1]*dd;
    int k  = offsets[j];
    int k1 = offsets[j+1];
    for (; k+8 <= k1; k += 8){
        int2 e0 = edge_s[k],   e1 = edge_s[k+1], e2 = edge_s[k+2], e3 = edge_s[k+3];
        int2 e4 = edge_s[k+4], e5 = edge_s[k+5], e6 = edge_s[k+6], e7 = edge_s[k+7];
        F16x2U a0, a1, a2, a3, a4, a5, a6, a7;
        a0.f = hlinH[(size_t)(e0.x & 0xFFFFFF)*32 + p];
        a1.f = hlinH[(size_t)(e1.x & 0xFFFFFF)*32 + p];
        a2.f = hlinH[(size_t)(e2.x & 0xFFFFFF)*32 + p];
        a3.f = hlinH[(size_t)(e3.x & 0xFFFFFF)*32 + p];
        a4.f = hlinH[(size_t)(e4.x & 0xFFFFFF)*32 + p];
        a5.f = hlinH[(size_t)(e5.x & 0xFFFFFF)*32 + p];
        a6.f = hlinH[(size_t)(e6.x & 0xFFFFFF)*32 + p];
        a7.f = hlinH[(size_t)(e7.x & 0xFFFFFF)*32 + p];
        float n0 = __int_as_float(e0.y), n1 = __int_as_float(e1.y);
        float n2 = __int_as_float(e2.y), n3 = __int_as_float(e3.y);
        float n4 = __int_as_float(e4.y), n5 = __int_as_float(e5.y);
        float n6 = __int_as_float(e6.y), n7 = __int_as_float(e7.y);
        ax += (float)a0.h[0]*n0; ay += (float)a0.h[1]*n0;
        ax += (float)a1.h[0]*n1; ay += (float)a1.h[1]*n1;
        ax += (float)a2.h[0]*n2; ay += (float)a2.h[1]*n2;
        ax += (float)a3.h[0]*n3; ay += (float)a3.h[1]*n3;
        ax += (float)a4.h[0]*n4; ay += (float)a4.h[1]*n4;
        ax += (float)a5.h[0]*n5; ay += (float)a5.h[1]*n5;
        ax += (float)a6.h[0]*n6; ay += (float)a6.h[1]*n6;
        ax += (float)a7.h[0]*n7; ay += (float)a7.h[1]*n7;
    }
    for (; k+4 <= k1; k += 4){
        int2 e0 = edge_s[k], e1 = edge_s[k+1], e2 = edge_s[k+2], e3 = edge_s[k+3];
        F16x2U a, b, c, e;
        a.f = hlinH[(size_t)(e0.x & 0xFFFFFF)*32 + p];
        b.f = hlinH[(size_t)(e1.x & 0xFFFFFF)*32 + p];
        c.f = hlinH[(size_t)(e2.x & 0xFFFFFF)*32 + p];
        e.f = hlinH[(size_t)(e3.x & 0xFFFFFF)*32 + p];
        float n0 = __int_as_float(e0.y), n1 = __int_as_float(e1.y);
        float n2 = __int_as_float(e2.y), n3 = __int_as_float(e3.y);
        ax += (float)a.h[0]*n0; ay += (float)a.h[1]*n0;
        ax += (float)b.h[0]*n1; ay += (float)b.h[1]*n1;
        ax += (float)c.h[0]*n2; ay += (float)c.h[1]*n2;
        ax += (float)e.h[0]*n3; ay += (float)e.h[1]*n3;
    }
    for (; k < k1; k++){
        int2 e0 = edge_s[k];
        F16x2U a; a.f = hlinH[(size_t)(e0.x & 0xFFFFFF)*32 + p];
        float n0 = __int_as_float(e0.y);
        ax += (float)a.h[0]*n0; ay += (float)a.h[1]*n0;
    }
    float2 bv = *(const float2*)&bias[2*p];
    float vx = fmaxf(ax + bv.x, 0.f);
    float vy = fmaxf(ay + bv.y, 0.f);
    F16x2U o; o.h[0] = (_Float16)vx; o.h[1] = (_Float16)vy;
    g2Hf[(size_t)j*32 + p] = o.f;
}

// ---------- BN2 stats over f16 output (12.3 MB pass) ----------
__global__ __launch_bounds__(256) void stats2h(
        const float* __restrict__ g2Hf, float* __restrict__ gsum2, float* __restrict__ gsq2){
    int p = threadIdx.x & 31;
    float s0 = 0.f, s1 = 0.f, q0 = 0.f, q1 = 0.f;
    int stride = gridDim.x*blockDim.x;   // multiple of 32 -> p constant
    for (int idx = blockIdx.x*blockDim.x + threadIdx.x; idx < N_NODES*32; idx += stride){
        F16x2U u; u.f = g2Hf[idx];
        float vx = (float)u.h[0], vy = (float)u.h[1];
        s0 += vx; q0 += vx*vx;
        s1 += vy; q1 += vy*vy;
    }
    __shared__ float sb[128];
    if (threadIdx.x < 128) sb[threadIdx.x] = 0.f;
    __syncthreads();
    atomicAdd(&sb[2*p],      s0);
    atomicAdd(&sb[2*p+1],    s1);
    atomicAdd(&sb[64+2*p],   q0);
    atomicAdd(&sb[64+2*p+1], q1);
    __syncthreads();
    if (threadIdx.x < 64){
        atomicAdd(&gsum2[threadIdx.x], sb[threadIdx.x]);
        atomicAdd(&gsq2[threadIdx.x],  sb[64+threadIdx.x]);
    }
}

// ---------- LSTM weight prep: B-fragment layout [K/32][256][32] f16 ----------
__global__ void prep_weights(const float* __restrict__ Wih1, const float* __restrict__ Whh1,
                             const float* __restrict__ bih1, const float* __restrict__ bhh1,
                             const float* __restrict__ Wih2, const float* __restrict__ Whh2,
                             const float* __restrict__ bih2, const float* __restrict__ bhh2,
                             _Float16* W1F, _Float16* W2F, float* b1c, float* b2c){
    int idx = blockIdx.x*blockDim.x + threadIdx.x;
    if (idx < 6*256*32){
        int kt = idx >> 13;
        int rem = idx & 8191;
        int n = rem >> 5, kin = rem & 31;
        int k = kt*32 + kin;
        float v = (k < 128) ? Wih1[n*128 + k] : Whh1[n*64 + (k-128)];
        W1F[idx] = (_Float16)v;
    }
    int i2 = idx - 6*256*32;
    if (i2 >= 0 && i2 < 4*256*32){
        int kt = i2 >> 13;
        int rem = i2 & 8191;
        int n = rem >> 5, kin = rem & 31;
        int k = kt*32 + kin;
        float v = (k < 64) ? Wih2[n*64 + k] : Whh2[n*64 + (k-64)];
        W2F[i2] = (_Float16)v;
    }
    int i3 = idx - (6*256*32 + 4*256*32);
    if (i3 >= 0 && i3 < 256) b1c[i3] = bih1[i3] + bhh1[i3];
    int i4 = i3 - 256;
    if (i4 >= 0 && i4 < 256) b2c[i4] = bih2[i4] + bhh2[i4];
}

// ---------- fused 12-step LSTM1+LSTM2, MFMA 16x16x32 f16, 32 rows/block ----------
// R21 known-good form VERBATIM (77.5us at fast clock, VGPR 196,
// 2 __syncthreads/step). R22 (gate-split, weights-in-reg) null; R23 (raw
// LDS barrier + sched_barrier) regressed. Structural floor -- do not touch.
#define X1S 200   // halves/row, 400 B
#define X2S 136   // halves/row, 272 B
__global__ __launch_bounds__(256) void lstm_fused(
        const _Float16* __restrict__ h1H, const _Float16* __restrict__ g2H,
        const float* __restrict__ gsum2, const float* __restrict__ gsq2,
        const float* __restrict__ g2bn, const float* __restrict__ be2,
        const _Float16* __restrict__ W1F, const _Float16* __restrict__ W2F,
        const float* __restrict__ b1c, const float* __restrict__ b2c,
        float* __restrict__ h1s, float* __restrict__ h2s){
    __shared__ _Float16 X1h[32*X1S];
    __shared__ _Float16 X2h[32*X2S];
    int tid = threadIdx.x;
    int j0 = blockIdx.x*32;
    int w    = tid >> 6;
    int lane = tid & 63;
    int quad = lane >> 4;
    int l16  = lane & 15;
    int u    = 16*w + l16;

    int c4 = tid & 15;
    int sr = (tid >> 4) & 15;          // this thread stages rows sr and sr+16
    int sjA = j0 + sr;
    int sjB = sjA + 16;
    int sbA = sjA / NN_SZ, snA = sjA - sbA*NN_SZ;
    int sbB = sjB / NN_SZ, snB = sjB - sbB*NN_SZ;   // block may straddle batch
    size_t rbaseA = ((size_t)(sbA*T_WIN)*NN_SZ + snA)*64 + c4*4;
    size_t rbaseB = ((size_t)(sbB*T_WIN)*NN_SZ + snB)*64 + c4*4;
    const size_t tstep = (size_t)NN_SZ*64;
    float sc2v[4], sh2v[4];
    #pragma unroll
    for (int q = 0; q < 4; q++){
        int f = c4*4 + q;
        float mean = gsum2[f]*(1.0f/(float)N_NODES);
        float var  = fmaxf(gsq2[f]*(1.0f/(float)N_NODES) - mean*mean, 0.f);
        float sc_  = g2bn[f]*rsqrtf(var + BN_EPS);
        sc2v[q] = sc_; sh2v[q] = be2[f] - mean*sc_;
    }

    float c1r[2][4], c2r[2][4], h2r[2][4];
    #pragma unroll
    for (int tle = 0; tle < 2; tle++)
        #pragma unroll
        for (int i = 0; i < 4; i++){ c1r[tle][i] = 0.f; c2r[tle][i] = 0.f; h2r[tle][i] = 0.f; }

    float bi1 = b1c[u], bf1 = b1c[64+u], bg1 = b1c[128+u], bo1 = b1c[192+u];
    float bi2 = b2c[u], bf2 = b2c[64+u], bg2 = b2c[128+u], bo2 = b2c[192+u];

    {
        half4 v0A = *(const half4*)&h1H[rbaseA];
        half4 g4A = *(const half4*)&g2H[rbaseA];
        half4 v0B = *(const half4*)&h1H[rbaseB];
        half4 g4B = *(const half4*)&g2H[rbaseB];
        half4 v1A, v1B;
        #pragma unroll
        for (int q = 0; q < 4; q++){
            v1A[q] = (_Float16)((float)g4A[q]*sc2v[q] + sh2v[q]);
            v1B[q] = (_Float16)((float)g4B[q]*sc2v[q] + sh2v[q]);
        }
        *(half4*)&X1h[sr*X1S + c4*4]             = v0A;
        *(half4*)&X1h[sr*X1S + 64 + c4*4]        = v1A;
        *(half4*)&X1h[sr*X1S + 128 + c4*4]       = (half4){0,0,0,0};
        *(half4*)&X1h[(sr+16)*X1S + c4*4]        = v0B;
        *(half4*)&X1h[(sr+16)*X1S + 64 + c4*4]   = v1B;
        *(half4*)&X1h[(sr+16)*X1S + 128 + c4*4]  = (half4){0,0,0,0};
    }
    __syncthreads();

    for (int t = 0; t < T_WIN; t++){
        half4 nv0A, ng4A, nv0B, ng4B;
        if (t < T_WIN-1){
            size_t rbA = rbaseA + (size_t)(t+1)*tstep;
            size_t rbB = rbaseB + (size_t)(t+1)*tstep;
            nv0A = *(const half4*)&h1H[rbA];
            ng4A = *(const half4*)&g2H[rbA];
            nv0B = *(const half4*)&h1H[rbB];
            ng4B = *(const half4*)&g2H[rbB];
        }

        // ---- phase 1: gates1 = X1 @ W1^T, K=192, 2 row-tiles per B-frag ----
        f32x4 acc[2][4];
        #pragma unroll
        for (int tle = 0; tle < 2; tle++)
            #pragma unroll
            for (int g = 0; g < 4; g++) acc[tle][g] = (f32x4){0.f,0.f,0.f,0.f};
        #pragma unroll
        for (int kt = 0; kt < 6; kt++){
            half8 a0 = *(const half8*)&X1h[l16*X1S + kt*32 + quad*8];
            half8 a1 = *(const half8*)&X1h[(l16+16)*X1S + kt*32 + quad*8];
            #pragma unroll
            for (int g = 0; g < 4; g++){
                half8 b = *(const half8*)&W1F[(size_t)(kt*256 + 64*g + u)*32 + quad*8];
                acc[0][g] = __builtin_amdgcn_mfma_f32_16x16x32_f16(a0, b, acc[0][g], 0, 0, 0);
                acc[1][g] = __builtin_amdgcn_mfma_f32_16x16x32_f16(a1, b, acc[1][g], 0, 0, 0);
            }
        }
        __syncthreads();

        // ---- cell update 1 (both tiles) + stage X2 + commit t+1 X1 ----
        #pragma unroll
        for (int tle = 0; tle < 2; tle++){
            #pragma unroll
            for (int r = 0; r < 4; r++){
                int rowl = quad*4 + r + 16*tle;
                float gi = acc[tle][0][r] + bi1;
                float gf = acc[tle][1][r] + bf1;
                float gg = acc[tle][2][r] + bg1;
                float go = acc[tle][3][r] + bo1;
                float cn = fsig(gf)*c1r[tle][r] + fsig(gi)*ftanh(gg);
                float hn = fsig(go)*ftanh(cn);
                c1r[tle][r] = cn;
                X2h[rowl*X2S + u]      = (_Float16)hn;
                X2h[rowl*X2S + 64 + u] = (_Float16)h2r[tle][r];
                X1h[rowl*X1S + 128 + u] = (_Float16)hn;
                if (t == T_WIN-1) h1s[(size_t)(j0 + rowl)*64 + u] = hn;
            }
        }
        if (t < T_WIN-1){
            half4 v1A, v1B;
            #pragma unroll
            for (int q = 0; q < 4; q++){
                v1A[q] = (_Float16)((float)ng4A[q]*sc2v[q] + sh2v[q]);
                v1B[q] = (_Float16)((float)ng4B[q]*sc2v[q] + sh2v[q]);
            }
            *(half4*)&X1h[sr*X1S + c4*4]            = nv0A;
            *(half4*)&X1h[sr*X1S + 64 + c4*4]       = v1A;
            *(half4*)&X1h[(sr+16)*X1S + c4*4]       = nv0B;
            *(half4*)&X1h[(sr+16)*X1S + 64 + c4*4]  = v1B;
        }
        __syncthreads();

        // ---- phase 2: gates2 = X2 @ W2^T, K=128 ----
        f32x4 acc2[2][4];
        #pragma unroll
        for (int tle = 0; tle < 2; tle++)
            #pragma unroll
            for (int g = 0; g < 4; g++) acc2[tle][g] = (f32x4){0.f,0.f,0.f,0.f};
        #pragma unroll
        for (int kt = 0; kt < 4; kt++){
            half8 a0 = *(const half8*)&X2h[l16*X2S + kt*32 + quad*8];
            half8 a1 = *(const half8*)&X2h[(l16+16)*X2S + kt*32 + quad*8];
            #pragma unroll
            for (int g = 0; g < 4; g++){
                half8 b = *(const half8*)&W2F[(size_t)(kt*256 + 64*g + u)*32 + quad*8];
                acc2[0][g] = __builtin_amdgcn_mfma_f32_16x16x32_f16(a0, b, acc2[0][g], 0, 0, 0);
                acc2[1][g] = __builtin_amdgcn_mfma_f32_16x16x32_f16(a1, b, acc2[1][g], 0, 0, 0);
            }
        }

        // ---- cell update 2 (both tiles) ----
        #pragma unroll
        for (int tle = 0; tle < 2; tle++){
            #pragma unroll
            for (int r = 0; r < 4; r++){
                int rowl = quad*4 + r + 16*tle;
                float gi = acc2[tle][0][r] + bi2;
                float gf = acc2[tle][1][r] + bf2;
                float gg = acc2[tle][2][r] + bg2;
                float go = acc2[tle][3][r] + bo2;
                float cn = fsig(gf)*c2r[tle][r] + fsig(gi)*ftanh(gg);
                float hn = fsig(go)*ftanh(cn);
                c2r[tle][r] = cn;
                h2r[tle][r] = hn;
                if (t == T_WIN-1) h2s[(size_t)(j0 + rowl)*64 + u] = hn;
            }
        }
    }
}

// ---------- FC head ----------
__global__ __launch_bounds__(256) void fc_head(
        const float* __restrict__ h1s, const float* __restrict__ h2s,
        const float* __restrict__ inner, const float* __restrict__ x,
        const float* __restrict__ fc1_w, const float* __restrict__ fc1_b,
        const float* __restrict__ fc3_w, const float* __restrict__ fc3_b,
        float* __restrict__ out){
    __shared__ float zsm[4][226];
    int wv = threadIdx.x >> 6;
    int f  = threadIdx.x & 63;
    int j  = blockIdx.x*4 + wv;
    int b = j / NN_SZ, n = j - b*NN_SZ;
    for (int k = f; k < 225; k += 64){
        float v;
        if (k < 64)        v = h1s[j*64 + k];
        else if (k < 128)  v = h2s[j*64 + (k-64)];
        else if (k == 128) v = inner[j];
        else {
            int kk = k - 129;
            int w_ = kk >> 3, ff = kk & 7;
            v = x[((b*T_WIN + w_)*NN_SZ + n)*FIN + ff];
        }
        zsm[wv][k] = v;
    }
    __syncthreads();
    float acc = fc1_b[f];
    for (int k = 0; k < 225; k++) acc += zsm[wv][k]*fc1_w[k*64 + f];
    float p = fmaxf(acc, 0.f) * fc3_w[f];
    #pragma unroll
    for (int off = 32; off > 0; off >>= 1) p += __shfl_down(p, off, 64);
    if (f == 0) out[j] = fmaxf(p + fc3_b[0], 0.f);
}

extern "C" void kernel_launch(void* const* d_in, const int* in_sizes, int n_in,
                              void* d_out, int out_size, void* d_ws, size_t ws_size,
                              hipStream_t stream){
    const int*   adj  = (const int*)d_in[0];
    const int*   row  = adj;
    const int*   col  = adj + EDGES;
    const float* aw   = (const float*)d_in[1];
    const float* x    = (const float*)d_in[2];
    const float* inner= (const float*)d_in[3];
    const float* W1   = (const float*)d_in[4];
    const float* b1   = (const float*)d_in[5];
    const float* W2   = (const float*)d_in[6];
    const float* b2   = (const float*)d_in[7];
    const float* g1   = (const float*)d_in[8];
    const float* be1  = (const float*)d_in[9];
    const float* g2   = (const float*)d_in[10];
    const float* be2  = (const float*)d_in[11];
    const float* Wih1 = (const float*)d_in[12];
    const float* Whh1 = (const float*)d_in[13];
    const float* bih1 = (const float*)d_in[14];
    const float* bhh1 = (const float*)d_in[15];
    const float* Wih2 = (const float*)d_in[16];
    const float* Whh2 = (const float*)d_in[17];
    const float* bih2 = (const float*)d_in[18];
    const float* bhh2 = (const float*)d_in[19];
    const float* fc1w = (const float*)d_in[20];
    const float* fc1b = (const float*)d_in[21];
    const float* fc3w = (const float*)d_in[22];
    const float* fc3b = (const float*)d_in[23];
    float* out = (float*)d_out;

    float* ws = (float*)d_ws;
    const size_t NB = (size_t)N_NODES*64;            // 12,288,000 floats
    float* bufX = ws;                                 // blockbase -> hlinH -> LSTM outs + W
    float* bufY = ws + NB;                            // rec -> g2H (f16)
    float* bufZ = ws + 2*NB;                          // h1H (f16) + ax
    int2*  edge_s  = (int2*)(ws + 3*NB);              // E int2
    float* degdis  = ws + 3*NB + (size_t)2*EDGES;     // N (dis)
    float* gsum    = degdis + N_NODES;                // 64
    float* gsq     = gsum + 64;                       // 64
    float* gsum2   = gsq + 64;                        // 64
    float* gsq2    = gsum2 + 64;                      // 64
    unsigned* gcount = (unsigned*)(gsq2 + 64);        // NBKT
    int* gbase   = (int*)(gcount + NBKT);             // NBKT+1
    int* offsets = gbase + (NBKT + 2);                // N+1
    _Float16* xh = (_Float16*)(offsets + (N_NODES + 2));  // N*8 f16 (3 MB)

    // preprocessing aliases (dead before their buffers' later users)
    int* blockbase = (int*)bufX;                      // NBLKA*NBKT ints (768 KB)
    int2* rec      = (int2*)bufY;                     // E int2 (16 MB)

    // phase-1 aliases
    float* hlinH = bufX;                              // N*32 floats (f16 pairs)
    _Float16* h1H = (_Float16*)bufZ;                  // N*64 f16
    float* ax    = bufZ + (size_t)N_NODES*32 + 64;    // N*8 fp32
    float* g2Hf  = bufY;                              // N*32 floats (f16 pairs)

    // LSTM-phase aliases into bufX (hlinH dead after gather2h)
    float* h1s = bufX;
    float* h2s = bufX + (size_t)BN_ROWS*64;
    _Float16* W1F = (_Float16*)(bufX + (size_t)4*BN_ROWS*64);
    _Float16* W2F = W1F + 6*256*32;
    float* b1c = (float*)(W2F + 4*256*32);
    float* b2c = b1c + 256;

    // ---- edge preprocessing: LDS-privatized two-level counting sort ----
    hipMemsetAsync(gcount, 0, NBKT*sizeof(unsigned), stream);
    hipMemsetAsync(gsum, 0, 256*sizeof(float), stream);   // gsum/gsq/gsum2/gsq2
    hist_coarse   <<<NBLKA, 256, 0, stream>>>(col, gcount, blockbase);
    scan_bkt      <<<1, 1024, 0, stream>>>(gcount, gbase, offsets);
    scatter_bucket<<<NBLKA, 256, 0, stream>>>(row, col, aw, blockbase, gbase, rec);
    bucket_deg    <<<NBKT, 256, 0, stream>>>(rec, gbase, degdis);
    bucket_csr    <<<NBKT, 256, 0, stream>>>(rec, gbase, degdis, edge_s, offsets);

    // ---- GCN layer 1 (node-parallel, f16 L2-resident gather table, ILP x8) ----
    x2h<<<N_NODES*8/1024, 256, 0, stream>>>(x, xh);
    aggx_k<<<N_NODES/32, 256, 0, stream>>>(offsets, edge_s, degdis, x, xh, ax);
    lin1b_stats<<<1024, 256, 0, stream>>>(ax, W1, b1, gsum, gsq);

    // ---- BN1 + layer-2 linear, gcn1 recomputed from ax (no 49MB intermediate) ----
    lin2_bn<<<N_NODES/L2ROWS, 128, 0, stream>>>(ax, W1, b1, gsum, gsq, g1, be1, W2, h1H, hlinH);

    // ---- GCN layer 2 (ILP x8) + separate f16 stats pass ----
    gather2h<<<N_NODES/8, 256, 0, stream>>>(offsets, edge_s, degdis, hlinH, b2, g2Hf);
    stats2h<<<1024, 256, 0, stream>>>(g2Hf, gsum2, gsq2);

    // ---- fused 12-step LSTM (32 rows/block, R21 known-good) ----
    prep_weights<<<(6*256*32 + 4*256*32 + 512 + 255)/256, 256, 0, stream>>>(
        Wih1, Whh1, bih1, bhh1, Wih2, Whh2, bih2, bhh2, W1F, W2F, b1c, b2c);
    lstm_fused<<<BN_ROWS/32, 256, 0, stream>>>(h1H, (const _Float16*)g2Hf,
                                               gsum2, gsq2, g2, be2,
                                               W1F, W2F, b1c, b2c, h1s, h2s);

    // ---- FC head ----
    fc_head<<<BN_ROWS/4, 256, 0, stream>>>(h1s, h2s, inner, x, fc1w, fc1b, fc3w, fc3b, out);
}